// Round 6
// baseline (211.601 us; speedup 1.0000x reference)
//
#include <hip/hip_runtime.h>
#include <stdint.h>

typedef unsigned short u16;
typedef __attribute__((ext_vector_type(8))) short bf16x8;
typedef __attribute__((ext_vector_type(4))) short bf16x4;
typedef __attribute__((ext_vector_type(4))) float f32x4;
typedef __attribute__((ext_vector_type(4))) unsigned short u16x4;

// async global->LDS, 16B per lane, dest = wave-uniform base + lane*16
#define GLD16(gp, lp) __builtin_amdgcn_global_load_lds( \
    (__attribute__((address_space(1))) void*)(void*)(gp), \
    (__attribute__((address_space(3))) void*)(void*)(lp), 16, 0, 0)

__device__ __forceinline__ u16 f2b(float f) {  // fp32 -> bf16 bits, RNE
  union { float f; unsigned u; } v; v.f = f;
  unsigned r = v.u + 0x7FFFu + ((v.u >> 16) & 1u);
  return (u16)(r >> 16);
}

__device__ __forceinline__ float fexp2(float x) {
#if __has_builtin(__builtin_amdgcn_exp2f)
  return __builtin_amdgcn_exp2f(x);
#else
  return exp2f(x);
#endif
}

// ============================ image layouts ================================
// h_img[bm 0..63][kt 0..7][half 0..1][128r][8 chunks x 8ch]:
//   half-panel = 8192 u16 (16 KB); phys chunk = c ^ (((r>>2)&1)<<1)  (st_16x32)
// w_img[bn 0..5][kt 0..7][half 0..1][128r][8 chunks], same swizzle.
// Staging a half-panel = 2 flat GLD16 per thread (8 KB per wave-instr set).
// ===========================================================================

// ---------------- fused: GroupNorm (blocks 0..511) + weight cvt (512..1535)
__global__ __launch_bounds__(256) void gncvt_kernel(const float* __restrict__ x,
                                                    const float* __restrict__ gw,
                                                    const float* __restrict__ gb,
                                                    u16* __restrict__ h,
                                                    const float* __restrict__ wq_f,
                                                    const float* __restrict__ wo_f,
                                                    u16* __restrict__ wq,
                                                    u16* __restrict__ wo) {
  if (blockIdx.x >= 512) {
    int i = (blockIdx.x - 512) * 256 + threadIdx.x;   // 0 .. 262143
    if (i < 196608) {
      // proj_w -> w_img: row n = i>>7, channels c0 = (i&127)*4
      const float4 f = ((const float4*)wq_f)[i];
      const int n = i >> 7, c0 = (i & 127) * 4;
      const int bn = n >> 8, half = (n >> 7) & 1, r = n & 127;
      const int kt = c0 >> 6, ch = (c0 >> 3) & 7, j = c0 & 7;
      const int sel2 = ((r >> 2) & 1) << 1;
      u16x4 rr; rr[0] = f2b(f.x); rr[1] = f2b(f.y); rr[2] = f2b(f.z); rr[3] = f2b(f.w);
      *(u16x4*)(wq + ((size_t)(bn * 8 + kt) * 2 + half) * 8192 + r * 64 + ((ch ^ sel2) * 8) + j) = rr;
    } else {
      int j = i - 196608;
      const float4 f = ((const float4*)wo_f)[j];
      u16x4 rr; rr[0] = f2b(f.x); rr[1] = f2b(f.y); rr[2] = f2b(f.z); rr[3] = f2b(f.w);
      *(u16x4*)(wo + (size_t)j * 4) = rr;
    }
    return;
  }
  const int b = blockIdx.x >> 5, g = blockIdx.x & 31;
  const float* xg = x + ((size_t)(b * 512 + g * 16)) * 1024;
  const int tid = threadIdx.x;
  float4 vals[16];                 // vals[j] = channel j, pixels 4t..4t+3
  float s = 0.f, ss = 0.f;
#pragma unroll
  for (int j = 0; j < 16; j++) {
    const float4 v = ((const float4*)xg)[j * 256 + tid];
    vals[j] = v;
    s  += (v.x + v.y) + (v.z + v.w);
    ss += (v.x * v.x + v.y * v.y) + (v.z * v.z + v.w * v.w);
  }
#pragma unroll
  for (int off = 32; off; off >>= 1) { s += __shfl_down(s, off); ss += __shfl_down(ss, off); }
  __shared__ float red[8];
  const int wid = tid >> 6, lane = tid & 63;
  if (lane == 0) { red[wid] = s; red[4 + wid] = ss; }
  __syncthreads();
  if (tid == 0) {
    float S = red[0] + red[1] + red[2] + red[3];
    float SS = red[4] + red[5] + red[6] + red[7];
    float mean = S * (1.f / 16384.f);
    float var = SS * (1.f / 16384.f) - mean * mean;
    red[0] = mean; red[1] = rsqrtf(var + 1e-5f);
  }
  __syncthreads();
  const float mean = red[0], rs = red[1];
  float sc[16], bi[16];
#pragma unroll
  for (int c = 0; c < 16; c++) { sc[c] = gw[g * 16 + c] * rs; bi[c] = gb[g * 16 + c]; }
  // write into h_img: block (b,g) owns kt = g>>2, chunks (g&3)*2, (g&3)*2+1
  const int kt = g >> 2;
  const int bmq = tid >> 6;                 // sp>>8
  const int half = (tid >> 5) & 1;          // sp>>7 & 1
  const int sel2 = (tid & 1) << 1;          // ((sp>>2)&1)<<1
  const int cph = (((g & 3) * 2) ^ sel2) * 8;
  u16* base = h + ((size_t)((b * 4 + bmq) * 8 + kt) * 2 + half) * 8192;
#pragma unroll
  for (int e = 0; e < 4; e++) {
    const int r = (tid & 31) * 4 + e;       // row within half-panel
    u16 row[16];
#pragma unroll
    for (int j = 0; j < 16; j++) {
      const float v = (e == 0) ? vals[j].x : (e == 1) ? vals[j].y : (e == 2) ? vals[j].z : vals[j].w;
      row[j] = f2b((v - mean) * sc[j] + bi[j]);
    }
    *(bf16x8*)(base + r * 64 + cph) = *(bf16x8*)&row[0];
    *(bf16x8*)(base + r * 64 + cph + 8) = *(bf16x8*)&row[8];
  }
}

// ---------------- QKV GEMM v5: m201-faithful 256^2 8-phase, counted vmcnt --
// M=16384, N=1536, K=512. grid (64,6)=384; 512 thr = 8 waves (2M x 4N),
// per-wave 128x64, acc[8][4]. LDS 128 KB: [2dbuf][2half][128][64] A and B.
// 4 phases/K-tile: {ds_read subtile || stage 1 half-tile -> barrier ->
// lgkmcnt(0) -> setprio(1) -> 16 MFMA -> setprio(0) -> barrier}.
// vmcnt(6) ONCE per K-tile (2 loads/half x 3 halves in flight) - never 0
// in the main loop (T4, the m218-isolated lever). st_16x32 swizzle baked
// into h_img/w_img, same XOR on ds_read side (T2).
__global__ __launch_bounds__(512, 2) void qkv_gemm(const u16* __restrict__ h,
                                                   const u16* __restrict__ w,
                                                   const float* __restrict__ bias,
                                                   u16* __restrict__ q,
                                                   u16* __restrict__ k,
                                                   u16* __restrict__ v) {
  __shared__ u16 As[2][16384];   // 2 x 32 KB
  __shared__ u16 Bs[2][16384];   // 2 x 32 KB
  const int bm = blockIdx.x;     // 0..63  (256 rows)
  const int bn = blockIdx.y;     // 0..5   (256 cols)
  const int tid = threadIdx.x, lane = tid & 63, wid = tid >> 6;
  const int wm = wid >> 2, wn = wid & 3;    // 2M x 4N waves, 128x64 each
  const int c15 = lane & 15, quad = lane >> 4;
  const int sel2 = ((c15 >> 2) & 1) << 1;
  const int ck0 = ((quad) ^ sel2) * 8;          // kk=0 chunk offset (u16)
  const int ck1 = ((4 + quad) ^ sel2) * 8;      // kk=1
  const u16* hA = h + (size_t)bm * 131072;      // + kt*16384 + half*8192
  const u16* wB = w + (size_t)bn * 131072;

  const int aBase = wm * 8192 + c15 * 64;                      // + (q*64+mi*16)*64
  const int bBase = (wn >> 1) * 8192 + ((wn & 1) * 64 + c15) * 64;   // + ni*16*64

  const f32x4 fz = {0.f, 0.f, 0.f, 0.f};
  f32x4 acc[8][4];
#pragma unroll
  for (int i = 0; i < 8; i++)
#pragma unroll
    for (int j = 0; j < 4; j++) acc[i][j] = fz;

  // prologue: stage tile 0 fully into buf 0
#pragma unroll
  for (int ht = 0; ht < 2; ht++) {
    GLD16(hA + ht * 8192 + tid * 8, &As[0][ht * 8192 + tid * 8]);
    GLD16(hA + ht * 8192 + 4096 + tid * 8, &As[0][ht * 8192 + 4096 + tid * 8]);
    GLD16(wB + ht * 8192 + tid * 8, &Bs[0][ht * 8192 + tid * 8]);
    GLD16(wB + ht * 8192 + 4096 + tid * 8, &Bs[0][ht * 8192 + 4096 + tid * 8]);
  }
  asm volatile("s_waitcnt vmcnt(0)" ::: "memory");
  __builtin_amdgcn_s_barrier();
  __builtin_amdgcn_sched_barrier(0);

#define STAGE_A(HT) { const u16* sp_ = hA + (size_t)(kt + 1) * 16384 + (HT) * 8192 + tid * 8; \
    GLD16(sp_, &As[db][(HT) * 8192 + tid * 8]); \
    GLD16(sp_ + 4096, &As[db][(HT) * 8192 + 4096 + tid * 8]); }
#define STAGE_B(HT) { const u16* sp_ = wB + (size_t)(kt + 1) * 16384 + (HT) * 8192 + tid * 8; \
    GLD16(sp_, &Bs[db][(HT) * 8192 + tid * 8]); \
    GLD16(sp_ + 4096, &Bs[db][(HT) * 8192 + 4096 + tid * 8]); }
#define PH_SYNC() { __builtin_amdgcn_s_barrier(); \
    asm volatile("s_waitcnt lgkmcnt(0)" ::: "memory"); \
    __builtin_amdgcn_sched_barrier(0); }
#define PH_END() { __builtin_amdgcn_s_barrier(); __builtin_amdgcn_sched_barrier(0); }

  for (int kt = 0; kt < 8; ++kt) {
    const int cb = kt & 1, db = cb ^ 1;
    const bool st = (kt < 7);
    bf16x8 af[2][4], bf01[2][2], bf23[2][2];

    // ---- phase 0: read af(lo rows) + bf(ni0,1); stage A-half0(kt+1)
#pragma unroll
    for (int mi = 0; mi < 4; mi++) {
      af[0][mi] = *(const bf16x8*)&As[cb][aBase + (mi * 16) * 64 + ck0];
      af[1][mi] = *(const bf16x8*)&As[cb][aBase + (mi * 16) * 64 + ck1];
    }
#pragma unroll
    for (int ni = 0; ni < 2; ni++) {
      bf01[0][ni] = *(const bf16x8*)&Bs[cb][bBase + (ni * 16) * 64 + ck0];
      bf01[1][ni] = *(const bf16x8*)&Bs[cb][bBase + (ni * 16) * 64 + ck1];
    }
    if (st) STAGE_A(0)
    PH_SYNC();
    __builtin_amdgcn_s_setprio(1);
#pragma unroll
    for (int kk = 0; kk < 2; kk++)
#pragma unroll
      for (int mi = 0; mi < 4; mi++)
#pragma unroll
        for (int ni = 0; ni < 2; ni++)
          acc[mi][ni] = __builtin_amdgcn_mfma_f32_16x16x32_bf16(af[kk][mi], bf01[kk][ni], acc[mi][ni], 0, 0, 0);
    __builtin_amdgcn_s_setprio(0);
    PH_END();

    // ---- phase 1: read bf(ni2,3); stage A-half1(kt+1)
#pragma unroll
    for (int ni = 0; ni < 2; ni++) {
      bf23[0][ni] = *(const bf16x8*)&Bs[cb][bBase + ((2 + ni) * 16) * 64 + ck0];
      bf23[1][ni] = *(const bf16x8*)&Bs[cb][bBase + ((2 + ni) * 16) * 64 + ck1];
    }
    if (st) STAGE_A(1)
    PH_SYNC();
    __builtin_amdgcn_s_setprio(1);
#pragma unroll
    for (int kk = 0; kk < 2; kk++)
#pragma unroll
      for (int mi = 0; mi < 4; mi++)
#pragma unroll
        for (int ni = 0; ni < 2; ni++)
          acc[mi][2 + ni] = __builtin_amdgcn_mfma_f32_16x16x32_bf16(af[kk][mi], bf23[kk][ni], acc[mi][2 + ni], 0, 0, 0);
    __builtin_amdgcn_s_setprio(0);
    PH_END();

    // ---- phase 2: read af(hi rows); stage B-half0(kt+1)
#pragma unroll
    for (int mi = 0; mi < 4; mi++) {
      af[0][mi] = *(const bf16x8*)&As[cb][aBase + (64 + mi * 16) * 64 + ck0];
      af[1][mi] = *(const bf16x8*)&As[cb][aBase + (64 + mi * 16) * 64 + ck1];
    }
    if (st) STAGE_B(0)
    PH_SYNC();
    __builtin_amdgcn_s_setprio(1);
#pragma unroll
    for (int kk = 0; kk < 2; kk++)
#pragma unroll
      for (int mi = 0; mi < 4; mi++)
#pragma unroll
        for (int ni = 0; ni < 2; ni++)
          acc[4 + mi][2 + ni] = __builtin_amdgcn_mfma_f32_16x16x32_bf16(af[kk][mi], bf23[kk][ni], acc[4 + mi][2 + ni], 0, 0, 0);
    __builtin_amdgcn_s_setprio(0);
    PH_END();

    // ---- phase 3: no reads (bf01 held); stage B-half1(kt+1); counted wait
    if (st) {
      STAGE_B(1)
      asm volatile("s_waitcnt vmcnt(6)" ::: "memory");   // 3 halves in flight
    }
    PH_SYNC();
    __builtin_amdgcn_s_setprio(1);
#pragma unroll
    for (int kk = 0; kk < 2; kk++)
#pragma unroll
      for (int mi = 0; mi < 4; mi++)
#pragma unroll
        for (int ni = 0; ni < 2; ni++)
          acc[4 + mi][ni] = __builtin_amdgcn_mfma_f32_16x16x32_bf16(af[kk][mi], bf01[kk][ni], acc[4 + mi][ni], 0, 0, 0);
    __builtin_amdgcn_s_setprio(0);
    PH_END();
  }
#undef STAGE_A
#undef STAGE_B
#undef PH_SYNC
#undef PH_END

  const float qscale = 0.51006972f;            // 2^-1.5 * log2(e)
  const float kscale = 0.35355339059327373f;   // 2^-1.5
  const int b = bm >> 2;
  const int quad4 = quad << 2;
#pragma unroll
  for (int a = 0; a < 8; a++) {
    const int sp = (bm & 3) * 256 + wm * 128 + (a >> 2) * 64 + (a & 3) * 16 + quad4;
#pragma unroll
    for (int ni = 0; ni < 4; ni++) {
      const int n = bn * 256 + wn * 64 + ni * 16 + c15;
      const int head = n / 192;
      const int rr = n - head * 192;
      const float bi = bias[n];
      const int d = rr & 63;
      if (rr < 128) {
        u16* dst = (rr < 64) ? q : k;
        const float sc = (rr < 64) ? qscale : kscale;
        dst += ((size_t)(b * 8 + head) * 1024 + sp) * 64 + d;
#pragma unroll
        for (int r = 0; r < 4; r++)
          dst[(size_t)r * 64] = f2b((acc[a][ni][r] + bi) * sc);
      } else {
        u16x4 pk;
#pragma unroll
        for (int r = 0; r < 4; r++) pk[r] = f2b(acc[a][ni][r] + bi);
        *(u16x4*)(v + ((size_t)(b * 8 + head) * 64 + d) * 1024 + sp) = pk;
      }
    }
  }
}

// ---------------- flash attention v10: 8-wave / 256-Q-row blocks ----------
__global__ __launch_bounds__(512) void attn_kernel(const u16* __restrict__ q,
                                                   const u16* __restrict__ k,
                                                   const u16* __restrict__ vT,
                                                   u16* __restrict__ o) {
  __shared__ u16 Ks[2][64 * 64];
  __shared__ u16 Vs[2][64 * 64];
  const int bh = blockIdx.x;
  const int qb = blockIdx.y;      // 0..3
  const int tid = threadIdx.x, lane = tid & 63, wid = tid >> 6;   // wid 0..7
  const u16* Q = q + (size_t)bh * 1024 * 64;
  const u16* K = k + (size_t)bh * 1024 * 64;
  const u16* V = vT + (size_t)bh * 64 * 1024;
  const int qrow0 = qb * 256 + wid * 32;
  const int c15 = lane & 15, quad = lane >> 4;
  const int sw = c15 & 7;                  // read-side swizzle component
  const int srow = tid >> 3;               // 0..63
  const int u8g  = tid & 7;                // 8-col group (K) / 8-key group (V)
  const int s7 = srow & 7;
  const int kld = srow * 64 + ((u8g ^ s7) * 8);
  const int ve = 4 * (u8g >> 2) + 2 * (u8g & 1);   // pc0>>1
  const int vc = ((u8g >> 1) & 1) * 4;             // (pc0&1)*4
  const int vld0 = srow * 64 + ((ve ^ s7) * 8) + vc;
  const int vld1 = srow * 64 + (((ve + 1) ^ s7) * 8) + vc;

  bf16x8 qf[2][2];
#pragma unroll
  for (int kk = 0; kk < 2; kk++)
#pragma unroll
    for (int ni = 0; ni < 2; ni++)
      qf[kk][ni] = *(const bf16x8*)(Q + (size_t)(qrow0 + ni * 16 + c15) * 64 + kk * 32 + quad * 8);

  const f32x4 fz = {0.f, 0.f, 0.f, 0.f};
  const float Mshift = 14.4269504089f;     // 10 * log2(e)
  const f32x4 fm = {-Mshift, -Mshift, -Mshift, -Mshift};
  f32x4 oaccT[4][2];               // O^T[d-tile nd][qrow-tile ni]
#pragma unroll
  for (int i = 0; i < 4; i++)
#pragma unroll
    for (int j = 0; j < 2; j++) oaccT[i][j] = fz;
  float lsum[2] = {0.f, 0.f};

  bf16x8 kr, vr;
  kr = *(const bf16x8*)(K + (size_t)srow * 64 + u8g * 8);
  vr = *(const bf16x8*)(V + (size_t)srow * 1024 + u8g * 8);
  {
    u16* Kd = Ks[0]; u16* Vd = Vs[0];
    *(bf16x8*)&Kd[kld] = kr;
    union { bf16x4 h[2]; bf16x8 v; } a; a.v = vr;
    *(bf16x4*)&Vd[vld0] = a.h[0];
    *(bf16x4*)&Vd[vld1] = a.h[1];
  }
  kr = *(const bf16x8*)(K + (size_t)(64 + srow) * 64 + u8g * 8);
  vr = *(const bf16x8*)(V + (size_t)srow * 1024 + 64 + u8g * 8);

  for (int kt = 0; kt < 16; ++kt) {
    __syncthreads();   // publish buf[kt&1]; retire readers of buf[(kt&1)^1]
    const int cur = kt & 1, alt = cur ^ 1;
    if (kt < 15) {
      u16* Kd = Ks[alt]; u16* Vd = Vs[alt];
      *(bf16x8*)&Kd[kld] = kr;
      union { bf16x4 h[2]; bf16x8 v; } a; a.v = vr;
      *(bf16x4*)&Vd[vld0] = a.h[0];
      *(bf16x4*)&Vd[vld1] = a.h[1];
      const int pk2 = (kt + 2) & 15;
      kr = *(const bf16x8*)(K + ((size_t)pk2 * 64 + srow) * 64 + u8g * 8);
      vr = *(const bf16x8*)(V + (size_t)srow * 1024 + pk2 * 64 + u8g * 8);
    }
    const u16* Kc = Ks[cur];
    const u16* Vc = Vs[cur];

    f32x4 sacc[4][2];
#pragma unroll
    for (int i = 0; i < 4; i++)
#pragma unroll
      for (int j = 0; j < 2; j++) sacc[i][j] = fm;
#pragma unroll
    for (int kk = 0; kk < 2; kk++) {
      bf16x8 af[4];
#pragma unroll
      for (int mi = 0; mi < 4; mi++)
        af[mi] = *(const bf16x8*)&Kc[(mi * 16 + c15) * 64 + (((kk * 4 + quad) ^ sw) * 8)];
      __builtin_amdgcn_s_setprio(1);
#pragma unroll
      for (int mi = 0; mi < 4; mi++)
#pragma unroll
        for (int ni = 0; ni < 2; ni++)
          sacc[mi][ni] = __builtin_amdgcn_mfma_f32_16x16x32_bf16(af[mi], qf[kk][ni], sacc[mi][ni], 0, 0, 0);
      __builtin_amdgcn_s_setprio(0);
    }

    unsigned pkd[4][2][2];   // [key-tile mi][ni][dword]
#pragma unroll
    for (int ni = 0; ni < 2; ni++) {
      float ls = 0.f;
#pragma unroll
      for (int mi = 0; mi < 4; mi++) {
        unsigned pu[4];
#pragma unroll
        for (int r = 0; r < 4; r++) {
          const float p = fexp2(sacc[mi][ni][r]);
          ls += p;
          union { float f; unsigned u; } c; c.f = p;
          pu[r] = c.u;
        }
        pkd[mi][ni][0] = __builtin_amdgcn_perm(pu[1], pu[0], 0x07060302u);
        pkd[mi][ni][1] = __builtin_amdgcn_perm(pu[3], pu[2], 0x07060302u);
      }
      lsum[ni] += ls;
    }

#pragma unroll
    for (int mg = 0; mg < 2; mg++) {
      union { unsigned u[4]; bf16x8 v; } bb[2];
#pragma unroll
      for (int ni = 0; ni < 2; ni++) {
        bb[ni].u[0] = pkd[2 * mg][ni][0];     bb[ni].u[1] = pkd[2 * mg][ni][1];
        bb[ni].u[2] = pkd[2 * mg + 1][ni][0]; bb[ni].u[3] = pkd[2 * mg + 1][ni][1];
      }
      bf16x8 aa[4];
#pragma unroll
      for (int nd = 0; nd < 4; nd++)
        aa[nd] = *(const bf16x8*)&Vc[(nd * 16 + c15) * 64 + (((mg * 4 + quad) ^ sw) * 8)];
      __builtin_amdgcn_s_setprio(1);
#pragma unroll
      for (int nd = 0; nd < 4; nd++)
#pragma unroll
        for (int ni = 0; ni < 2; ni++)
          oaccT[nd][ni] = __builtin_amdgcn_mfma_f32_16x16x32_bf16(aa[nd], bb[ni].v, oaccT[nd][ni], 0, 0, 0);
      __builtin_amdgcn_s_setprio(0);
    }
  }

  float iv[2];
#pragma unroll
  for (int ni = 0; ni < 2; ni++) {
    float l = lsum[ni];
    l += __shfl_xor(l, 16);
    l += __shfl_xor(l, 32);
    iv[ni] = 1.f / l;
  }
  const int b = bh >> 3, hh = bh & 7;
#pragma unroll
  for (int ni = 0; ni < 2; ni++) {
    const int row = qrow0 + ni * 16 + c15;
#pragma unroll
    for (int nd = 0; nd < 4; nd++) {
      u16x4 pk4;
#pragma unroll
      for (int r = 0; r < 4; r++) pk4[r] = f2b(oaccT[nd][ni][r] * iv[ni]);
      *(u16x4*)(o + ((size_t)b * 1024 + row) * 512 + hh * 64 + nd * 16 + quad * 4) = pk4;
    }
  }
}

// ---------------- out proj, D[s][c] orientation + float4 residual epilogue -
__global__ __launch_bounds__(256) void out_gemm(const u16* __restrict__ attn,
                                                const u16* __restrict__ wo,
                                                const float* __restrict__ ob,
                                                const float* __restrict__ x,
                                                float* __restrict__ out) {
  __shared__ u16 As[128 * 32];
  __shared__ u16 Bs[128 * 32];
  const int b = blockIdx.z;
  const int bm = blockIdx.x;      // s-tile 0..7
  const int bn = blockIdx.y;      // c-tile 0..3
  const int tid = threadIdx.x, lane = tid & 63, wid = tid >> 6;
  const int wm = wid & 1, wn = wid >> 1;
  const u16* gA = attn + ((size_t)b * 1024 + bm * 128) * 512;
  const u16* gB = wo + (size_t)bn * 128 * 512;

  const f32x4 fz = {0.f, 0.f, 0.f, 0.f};
  f32x4 acc[4][4];
#pragma unroll
  for (int i = 0; i < 4; i++)
#pragma unroll
    for (int j = 0; j < 4; j++) acc[i][j] = fz;

  const int r0 = lane >> 2;
  const int ch8 = (lane & 3) * 8;

  for (int kt = 0; kt < 16; ++kt) {
    __syncthreads();
#pragma unroll
    for (int j = 0; j < 2; ++j) {
      const int idx = wid * 2 + j;
      const int row = idx * 16 + r0;
      GLD16(gA + (size_t)row * 512 + kt * 32 + ch8, &As[idx * 512 + lane * 8]);
      GLD16(gB + (size_t)row * 512 + kt * 32 + ch8, &Bs[idx * 512 + lane * 8]);
    }
    __syncthreads();
    bf16x8 af[4], bf[4];
#pragma unroll
    for (int mi = 0; mi < 4; mi++)
      af[mi] = *(const bf16x8*)&As[(wm * 64 + mi * 16 + (lane & 15)) * 32 + (lane >> 4) * 8];
#pragma unroll
    for (int ni = 0; ni < 4; ni++)
      bf[ni] = *(const bf16x8*)&Bs[(wn * 64 + ni * 16 + (lane & 15)) * 32 + (lane >> 4) * 8];
#pragma unroll
    for (int mi = 0; mi < 4; mi++)
#pragma unroll
      for (int ni = 0; ni < 4; ni++)
        acc[mi][ni] = __builtin_amdgcn_mfma_f32_16x16x32_bf16(af[mi], bf[ni], acc[mi][ni], 0, 0, 0);
  }

  const int quad4 = (lane >> 4) << 2;
  const int c15_ = lane & 15;
#pragma unroll
  for (int mi = 0; mi < 4; mi++) {
    const int m = bm * 128 + wm * 64 + mi * 16 + quad4;   // s base (rows m..m+3)
#pragma unroll
    for (int ni = 0; ni < 4; ni++) {
      const int c = bn * 128 + wn * 64 + ni * 16 + c15_;
      const float bo = ob[c];
      const size_t idx = ((size_t)b * 512 + c) * 1024 + m;
      const float4 xv = *(const float4*)(x + idx);
      float4 ov;
      ov.x = acc[mi][ni][0] + bo + xv.x;
      ov.y = acc[mi][ni][1] + bo + xv.y;
      ov.z = acc[mi][ni][2] + bo + xv.z;
      ov.w = acc[mi][ni][3] + bo + xv.w;
      *(float4*)(out + idx) = ov;
    }
  }
}

extern "C" void kernel_launch(void* const* d_in, const int* in_sizes, int n_in,
                              void* d_out, int out_size, void* d_ws, size_t ws_size,
                              hipStream_t stream) {
  const float* x      = (const float*)d_in[0];
  const float* gn_w   = (const float*)d_in[1];
  const float* gn_b   = (const float*)d_in[2];
  const float* proj_w = (const float*)d_in[3];
  const float* proj_b = (const float*)d_in[4];
  const float* out_w  = (const float*)d_in[5];
  const float* out_b  = (const float*)d_in[6];
  float* out = (float*)d_out;

  char* p = (char*)d_ws;
  u16* h    = (u16*)p; p += (size_t)16 * 1024 * 512 * 2;   // h_img [64bm][8kt][2half][8192]
  u16* q    = (u16*)p; p += (size_t)16 * 8 * 1024 * 64 * 2;
  u16* k    = (u16*)p; p += (size_t)16 * 8 * 1024 * 64 * 2;
  u16* v    = (u16*)p; p += (size_t)16 * 8 * 1024 * 64 * 2;   // [B,H,D,S]
  u16* attn = (u16*)p; p += (size_t)16 * 1024 * 512 * 2;
  u16* wq   = (u16*)p; p += (size_t)1536 * 512 * 2;           // w_img [6bn][8kt][2half][8192]
  u16* wo   = (u16*)p; p += (size_t)512 * 512 * 2;

  gncvt_kernel<<<1536, 256, 0, stream>>>(x, gn_w, gn_b, h, proj_w, out_w, wq, wo);
  qkv_gemm<<<dim3(64, 6), 512, 0, stream>>>(h, wq, proj_b, q, k, v);
  attn_kernel<<<dim3(128, 4), 512, 0, stream>>>(q, k, v, attn);
  out_gemm<<<dim3(8, 4, 16), 256, 0, stream>>>(attn, wo, out_b, x, out);
}

// Round 7
// 198.473 us; speedup vs baseline: 1.0661x; 1.0661x over previous
//
#include <hip/hip_runtime.h>
#include <stdint.h>

typedef unsigned short u16;
typedef __attribute__((ext_vector_type(8))) short bf16x8;
typedef __attribute__((ext_vector_type(4))) short bf16x4;
typedef __attribute__((ext_vector_type(4))) float f32x4;
typedef __attribute__((ext_vector_type(4))) unsigned short u16x4;

// async global->LDS, 16B per lane, dest = wave-uniform base + lane*16
#define GLD16(gp, lp) __builtin_amdgcn_global_load_lds( \
    (__attribute__((address_space(1))) void*)(void*)(gp), \
    (__attribute__((address_space(3))) void*)(void*)(lp), 16, 0, 0)

__device__ __forceinline__ u16 f2b(float f) {  // fp32 -> bf16 bits, RNE
  union { float f; unsigned u; } v; v.f = f;
  unsigned r = v.u + 0x7FFFu + ((v.u >> 16) & 1u);
  return (u16)(r >> 16);
}

__device__ __forceinline__ float fexp2(float x) {
#if __has_builtin(__builtin_amdgcn_exp2f)
  return __builtin_amdgcn_exp2f(x);
#else
  return exp2f(x);
#endif
}

// ============================ LDS-image layouts ============================
// h_img[mt 0..63][kt 0..15][256r x 4chunks]: panel = 8192 u16 (16 KB).
//   slot(r, c8, j) = r*32 + ((c8 ^ ((r>>1)&3))*8) + j    (c8 = 8-ch chunk)
// w_img[nt 0..15][kt 0..15][96r x 4chunks]: panel = 3072 u16 (6 KB), same
//   per-row swizzle. Staging a panel = flat GLD16 copy (1 KB/wave-instr).
// ===========================================================================

// ---------------- fused: GroupNorm (blocks 0..511) + weight cvt (512..1535)
__global__ __launch_bounds__(256) void gncvt_kernel(const float* __restrict__ x,
                                                    const float* __restrict__ gw,
                                                    const float* __restrict__ gb,
                                                    u16* __restrict__ h,
                                                    const float* __restrict__ wq_f,
                                                    const float* __restrict__ wo_f,
                                                    u16* __restrict__ wq,
                                                    u16* __restrict__ wo) {
  if (blockIdx.x >= 512) {
    int i = (blockIdx.x - 512) * 256 + threadIdx.x;   // 0 .. 262143
    if (i < 196608) {
      // proj_w -> w_img: row n = i>>7, channels c0 = (i&127)*4
      const float4 f = ((const float4*)wq_f)[i];
      const int n = i >> 7, c0 = (i & 127) * 4;
      const int nt = n / 96, r = n - nt * 96;
      const int kt = c0 >> 5, c8 = (c0 >> 3) & 3, wi = c0 & 7;
      const int sel = (r >> 1) & 3;
      u16x4 rr; rr[0] = f2b(f.x); rr[1] = f2b(f.y); rr[2] = f2b(f.z); rr[3] = f2b(f.w);
      *(u16x4*)(wq + (size_t)(nt * 16 + kt) * 3072 + r * 32 + ((c8 ^ sel) * 8) + wi) = rr;
    } else {
      int j = i - 196608;
      const float4 f = ((const float4*)wo_f)[j];
      u16x4 rr; rr[0] = f2b(f.x); rr[1] = f2b(f.y); rr[2] = f2b(f.z); rr[3] = f2b(f.w);
      *(u16x4*)(wo + (size_t)j * 4) = rr;
    }
    return;
  }
  const int b = blockIdx.x >> 5, g = blockIdx.x & 31;
  const float* xg = x + ((size_t)(b * 512 + g * 16)) * 1024;
  const int tid = threadIdx.x;
  float4 vals[16];                 // vals[j] = channel j, pixels 4t..4t+3
  float s = 0.f, ss = 0.f;
#pragma unroll
  for (int j = 0; j < 16; j++) {
    const float4 v = ((const float4*)xg)[j * 256 + tid];
    vals[j] = v;
    s  += (v.x + v.y) + (v.z + v.w);
    ss += (v.x * v.x + v.y * v.y) + (v.z * v.z + v.w * v.w);
  }
#pragma unroll
  for (int off = 32; off; off >>= 1) { s += __shfl_down(s, off); ss += __shfl_down(ss, off); }
  __shared__ float red[8];
  const int wid = tid >> 6, lane = tid & 63;
  if (lane == 0) { red[wid] = s; red[4 + wid] = ss; }
  __syncthreads();
  if (tid == 0) {
    float S = red[0] + red[1] + red[2] + red[3];
    float SS = red[4] + red[5] + red[6] + red[7];
    float mean = S * (1.f / 16384.f);
    float var = SS * (1.f / 16384.f) - mean * mean;
    red[0] = mean; red[1] = rsqrtf(var + 1e-5f);
  }
  __syncthreads();
  const float mean = red[0], rs = red[1];
  float sc[16], bi[16];
#pragma unroll
  for (int c = 0; c < 16; c++) { sc[c] = gw[g * 16 + c] * rs; bi[c] = gb[g * 16 + c]; }
  // write into h_img: this block owns chunks {2(g&1), 2(g&1)+1} of kt = g>>1
  const int mt = b * 4 + (tid >> 6);
  const int kt = g >> 1, c8a = (g & 1) * 2;
  u16* base = h + (size_t)(mt * 16 + kt) * 8192;
#pragma unroll
  for (int e = 0; e < 4; e++) {
    const int r = (tid & 63) * 4 + e;
    const int sel = (r >> 1) & 3;
    u16 row[16];
#pragma unroll
    for (int j = 0; j < 16; j++) {
      const float v = (e == 0) ? vals[j].x : (e == 1) ? vals[j].y : (e == 2) ? vals[j].z : vals[j].w;
      row[j] = f2b((v - mean) * sc[j] + bi[j]);
    }
    *(bf16x8*)(base + r * 32 + ((c8a ^ sel) * 8)) = *(bf16x8*)&row[0];
    *(bf16x8*)(base + r * 32 + (((c8a + 1) ^ sel) * 8)) = *(bf16x8*)&row[8];
  }
}

// ---------------- QKV GEMM v6: r5 core + SWAPPED orientation D[ch][s] -----
// Identical staging/schedule/swizzle/grid to the 48.0us r5 kernel; the ONLY
// change: A-operand = w-panel (channel rows), B-operand = h-panel (s cols),
// so each lane's 4 acc rows = 4 consecutive d-channels. q/k (2/3 of outputs)
// store as u16x4 (was 4x scalar u16); v (1/3) becomes the 32B-contiguous
// scalar pattern. Single-variable A/B vs r5 to ablate the epilogue-scatter
// hypothesis (the one invariant across all six 48-53us qkv versions).
__global__ __launch_bounds__(512, 4) void qkv_gemm(const u16* __restrict__ h,
                                                   const u16* __restrict__ w,
                                                   const float* __restrict__ bias,
                                                   u16* __restrict__ q,
                                                   u16* __restrict__ k,
                                                   u16* __restrict__ v) {
  __shared__ u16 Hs[2][8192];   // 2 x 16 KB  (h panels: 256 s-rows x 32 ch)
  __shared__ u16 Ws[2][3072];   // 2 x 6 KB   (w panels: 96 ch-rows x 32 ch)
  const int bm = blockIdx.x;    // 0..63  (256 s)
  const int bn = blockIdx.y;    // 0..15  (96 channels)
  const int tid = threadIdx.x, lane = tid & 63, wid = tid >> 6;
  const int wm = wid >> 1, wn = wid & 1;     // wm: 4 s-col waves, wn: 2 ch-row waves
  const int c15 = lane & 15, quad = lane >> 4;
  const int kc = ((quad ^ ((c15 >> 1) & 3)) * 8);   // phys chunk offset (u16)

  const u16* pA = h + (size_t)bm * 16 * 8192 + (size_t)tid * 8;   // + kt*8192
  const u16* pB = w + (size_t)bn * 16 * 3072 + (size_t)tid * 8;   // + kt*3072
  const bool doB = (tid < 384);

  const f32x4 fz = {0.f, 0.f, 0.f, 0.f};
  f32x4 acc[3][4];              // [ch-tile ci][s-tile si]
#pragma unroll
  for (int i = 0; i < 3; i++)
#pragma unroll
    for (int j = 0; j < 4; j++) acc[i][j] = fz;

  // prologue: stage kt=0 into buf 0
  GLD16(pA, &Hs[0][tid * 8]);
  GLD16(pA + 4096, &Hs[0][4096 + tid * 8]);
  if (doB) GLD16(pB, &Ws[0][tid * 8]);
  asm volatile("s_waitcnt vmcnt(0)" ::: "memory");
  __builtin_amdgcn_s_barrier();
  __builtin_amdgcn_sched_barrier(0);

  for (int kt = 0; kt < 16; ++kt) {
    const int cb = kt & 1, db = cb ^ 1;
    if (kt < 15) {   // issue next panel first; ages across this tile's MFMAs
      const u16* nA = pA + (size_t)(kt + 1) * 8192;
      GLD16(nA, &Hs[db][tid * 8]);
      GLD16(nA + 4096, &Hs[db][4096 + tid * 8]);
      if (doB) GLD16(pB + (size_t)(kt + 1) * 3072, &Ws[db][tid * 8]);
      __builtin_amdgcn_sched_barrier(0);
    }
    bf16x8 af[3], bf[4];
#pragma unroll
    for (int ci = 0; ci < 3; ci++)
      af[ci] = *(const bf16x8*)&Ws[cb][(wn * 48 + ci * 16 + c15) * 32 + kc];
#pragma unroll
    for (int si = 0; si < 4; si++)
      bf[si] = *(const bf16x8*)&Hs[cb][(wm * 64 + si * 16 + c15) * 32 + kc];
    __builtin_amdgcn_s_setprio(1);
#pragma unroll
    for (int ci = 0; ci < 3; ci++)
#pragma unroll
      for (int si = 0; si < 4; si++)
        acc[ci][si] = __builtin_amdgcn_mfma_f32_16x16x32_bf16(af[ci], bf[si], acc[ci][si], 0, 0, 0);
    __builtin_amdgcn_s_setprio(0);
    asm volatile("s_waitcnt vmcnt(0)" ::: "memory");   // aged ~full tile
    __builtin_amdgcn_s_barrier();
    __builtin_amdgcn_sched_barrier(0);
  }

  const float qscale = 0.51006972f;            // 2^-1.5 * log2(e)
  const float kscale = 0.35355339059327373f;   // 2^-1.5
  const int b = bm >> 2;
#pragma unroll
  for (int ci = 0; ci < 3; ci++) {
    const int n0 = bn * 96 + wn * 48 + ci * 16 + quad * 4;   // rows n0..n0+3
    const int head = n0 / 192;
    const int rr = n0 - head * 192;
    const int d0 = rr & 63;
    const float4 bi4 = *(const float4*)&bias[n0];
    const float bb[4] = {bi4.x, bi4.y, bi4.z, bi4.w};
#pragma unroll
    for (int si = 0; si < 4; si++) {
      const int sp = (bm & 3) * 256 + wm * 64 + si * 16 + c15;
      if (rr < 128) {
        u16* dst = ((rr < 64) ? q : k) + ((size_t)(b * 8 + head) * 1024 + sp) * 64 + d0;
        const float sc = (rr < 64) ? qscale : kscale;
        u16x4 pk;
#pragma unroll
        for (int r = 0; r < 4; r++) pk[r] = f2b((acc[ci][si][r] + bb[r]) * sc);
        *(u16x4*)dst = pk;
      } else {
#pragma unroll
        for (int r = 0; r < 4; r++)
          v[((size_t)(b * 8 + head) * 64 + d0 + r) * 1024 + sp] = f2b(acc[ci][si][r] + bb[r]);
      }
    }
  }
}

// ---------------- flash attention v10: 8-wave / 256-Q-row blocks ----------
__global__ __launch_bounds__(512) void attn_kernel(const u16* __restrict__ q,
                                                   const u16* __restrict__ k,
                                                   const u16* __restrict__ vT,
                                                   u16* __restrict__ o) {
  __shared__ u16 Ks[2][64 * 64];
  __shared__ u16 Vs[2][64 * 64];
  const int bh = blockIdx.x;
  const int qb = blockIdx.y;      // 0..3
  const int tid = threadIdx.x, lane = tid & 63, wid = tid >> 6;   // wid 0..7
  const u16* Q = q + (size_t)bh * 1024 * 64;
  const u16* K = k + (size_t)bh * 1024 * 64;
  const u16* V = vT + (size_t)bh * 64 * 1024;
  const int qrow0 = qb * 256 + wid * 32;
  const int c15 = lane & 15, quad = lane >> 4;
  const int sw = c15 & 7;                  // read-side swizzle component
  const int srow = tid >> 3;               // 0..63
  const int u8g  = tid & 7;                // 8-col group (K) / 8-key group (V)
  const int s7 = srow & 7;
  const int kld = srow * 64 + ((u8g ^ s7) * 8);
  const int ve = 4 * (u8g >> 2) + 2 * (u8g & 1);   // pc0>>1
  const int vc = ((u8g >> 1) & 1) * 4;             // (pc0&1)*4
  const int vld0 = srow * 64 + ((ve ^ s7) * 8) + vc;
  const int vld1 = srow * 64 + (((ve + 1) ^ s7) * 8) + vc;

  bf16x8 qf[2][2];
#pragma unroll
  for (int kk = 0; kk < 2; kk++)
#pragma unroll
    for (int ni = 0; ni < 2; ni++)
      qf[kk][ni] = *(const bf16x8*)(Q + (size_t)(qrow0 + ni * 16 + c15) * 64 + kk * 32 + quad * 8);

  const f32x4 fz = {0.f, 0.f, 0.f, 0.f};
  const float Mshift = 14.4269504089f;     // 10 * log2(e)
  const f32x4 fm = {-Mshift, -Mshift, -Mshift, -Mshift};
  f32x4 oaccT[4][2];               // O^T[d-tile nd][qrow-tile ni]
#pragma unroll
  for (int i = 0; i < 4; i++)
#pragma unroll
    for (int j = 0; j < 2; j++) oaccT[i][j] = fz;
  float lsum[2] = {0.f, 0.f};

  bf16x8 kr, vr;
  kr = *(const bf16x8*)(K + (size_t)srow * 64 + u8g * 8);
  vr = *(const bf16x8*)(V + (size_t)srow * 1024 + u8g * 8);
  {
    u16* Kd = Ks[0]; u16* Vd = Vs[0];
    *(bf16x8*)&Kd[kld] = kr;
    union { bf16x4 h[2]; bf16x8 v; } a; a.v = vr;
    *(bf16x4*)&Vd[vld0] = a.h[0];
    *(bf16x4*)&Vd[vld1] = a.h[1];
  }
  kr = *(const bf16x8*)(K + (size_t)(64 + srow) * 64 + u8g * 8);
  vr = *(const bf16x8*)(V + (size_t)srow * 1024 + 64 + u8g * 8);

  for (int kt = 0; kt < 16; ++kt) {
    __syncthreads();   // publish buf[kt&1]; retire readers of buf[(kt&1)^1]
    const int cur = kt & 1, alt = cur ^ 1;
    if (kt < 15) {
      u16* Kd = Ks[alt]; u16* Vd = Vs[alt];
      *(bf16x8*)&Kd[kld] = kr;
      union { bf16x4 h[2]; bf16x8 v; } a; a.v = vr;
      *(bf16x4*)&Vd[vld0] = a.h[0];
      *(bf16x4*)&Vd[vld1] = a.h[1];
      const int pk2 = (kt + 2) & 15;
      kr = *(const bf16x8*)(K + ((size_t)pk2 * 64 + srow) * 64 + u8g * 8);
      vr = *(const bf16x8*)(V + (size_t)srow * 1024 + pk2 * 64 + u8g * 8);
    }
    const u16* Kc = Ks[cur];
    const u16* Vc = Vs[cur];

    f32x4 sacc[4][2];
#pragma unroll
    for (int i = 0; i < 4; i++)
#pragma unroll
      for (int j = 0; j < 2; j++) sacc[i][j] = fm;
#pragma unroll
    for (int kk = 0; kk < 2; kk++) {
      bf16x8 af[4];
#pragma unroll
      for (int mi = 0; mi < 4; mi++)
        af[mi] = *(const bf16x8*)&Kc[(mi * 16 + c15) * 64 + (((kk * 4 + quad) ^ sw) * 8)];
      __builtin_amdgcn_s_setprio(1);
#pragma unroll
      for (int mi = 0; mi < 4; mi++)
#pragma unroll
        for (int ni = 0; ni < 2; ni++)
          sacc[mi][ni] = __builtin_amdgcn_mfma_f32_16x16x32_bf16(af[mi], qf[kk][ni], sacc[mi][ni], 0, 0, 0);
      __builtin_amdgcn_s_setprio(0);
    }

    unsigned pkd[4][2][2];   // [key-tile mi][ni][dword]
#pragma unroll
    for (int ni = 0; ni < 2; ni++) {
      float ls = 0.f;
#pragma unroll
      for (int mi = 0; mi < 4; mi++) {
        unsigned pu[4];
#pragma unroll
        for (int r = 0; r < 4; r++) {
          const float p = fexp2(sacc[mi][ni][r]);
          ls += p;
          union { float f; unsigned u; } c; c.f = p;
          pu[r] = c.u;
        }
        pkd[mi][ni][0] = __builtin_amdgcn_perm(pu[1], pu[0], 0x07060302u);
        pkd[mi][ni][1] = __builtin_amdgcn_perm(pu[3], pu[2], 0x07060302u);
      }
      lsum[ni] += ls;
    }

#pragma unroll
    for (int mg = 0; mg < 2; mg++) {
      union { unsigned u[4]; bf16x8 v; } bb[2];
#pragma unroll
      for (int ni = 0; ni < 2; ni++) {
        bb[ni].u[0] = pkd[2 * mg][ni][0];     bb[ni].u[1] = pkd[2 * mg][ni][1];
        bb[ni].u[2] = pkd[2 * mg + 1][ni][0]; bb[ni].u[3] = pkd[2 * mg + 1][ni][1];
      }
      bf16x8 aa[4];
#pragma unroll
      for (int nd = 0; nd < 4; nd++)
        aa[nd] = *(const bf16x8*)&Vc[(nd * 16 + c15) * 64 + (((mg * 4 + quad) ^ sw) * 8)];
      __builtin_amdgcn_s_setprio(1);
#pragma unroll
      for (int nd = 0; nd < 4; nd++)
#pragma unroll
        for (int ni = 0; ni < 2; ni++)
          oaccT[nd][ni] = __builtin_amdgcn_mfma_f32_16x16x32_bf16(aa[nd], bb[ni].v, oaccT[nd][ni], 0, 0, 0);
      __builtin_amdgcn_s_setprio(0);
    }
  }

  float iv[2];
#pragma unroll
  for (int ni = 0; ni < 2; ni++) {
    float l = lsum[ni];
    l += __shfl_xor(l, 16);
    l += __shfl_xor(l, 32);
    iv[ni] = 1.f / l;
  }
  const int b = bh >> 3, hh = bh & 7;
#pragma unroll
  for (int ni = 0; ni < 2; ni++) {
    const int row = qrow0 + ni * 16 + c15;
#pragma unroll
    for (int nd = 0; nd < 4; nd++) {
      u16x4 pk4;
#pragma unroll
      for (int r = 0; r < 4; r++) pk4[r] = f2b(oaccT[nd][ni][r] * iv[ni]);
      *(u16x4*)(o + ((size_t)b * 1024 + row) * 512 + hh * 64 + nd * 16 + quad * 4) = pk4;
    }
  }
}

// ---------------- out proj, D[s][c] orientation + float4 residual epilogue -
__global__ __launch_bounds__(256) void out_gemm(const u16* __restrict__ attn,
                                                const u16* __restrict__ wo,
                                                const float* __restrict__ ob,
                                                const float* __restrict__ x,
                                                float* __restrict__ out) {
  __shared__ u16 As[128 * 32];
  __shared__ u16 Bs[128 * 32];
  const int b = blockIdx.z;
  const int bm = blockIdx.x;      // s-tile 0..7
  const int bn = blockIdx.y;      // c-tile 0..3
  const int tid = threadIdx.x, lane = tid & 63, wid = tid >> 6;
  const int wm = wid & 1, wn = wid >> 1;
  const u16* gA = attn + ((size_t)b * 1024 + bm * 128) * 512;
  const u16* gB = wo + (size_t)bn * 128 * 512;

  const f32x4 fz = {0.f, 0.f, 0.f, 0.f};
  f32x4 acc[4][4];
#pragma unroll
  for (int i = 0; i < 4; i++)
#pragma unroll
    for (int j = 0; j < 4; j++) acc[i][j] = fz;

  const int r0 = lane >> 2;
  const int ch8 = (lane & 3) * 8;

  for (int kt = 0; kt < 16; ++kt) {
    __syncthreads();
#pragma unroll
    for (int j = 0; j < 2; ++j) {
      const int idx = wid * 2 + j;
      const int row = idx * 16 + r0;
      GLD16(gA + (size_t)row * 512 + kt * 32 + ch8, &As[idx * 512 + lane * 8]);
      GLD16(gB + (size_t)row * 512 + kt * 32 + ch8, &Bs[idx * 512 + lane * 8]);
    }
    __syncthreads();
    bf16x8 af[4], bf[4];
#pragma unroll
    for (int mi = 0; mi < 4; mi++)
      af[mi] = *(const bf16x8*)&As[(wm * 64 + mi * 16 + (lane & 15)) * 32 + (lane >> 4) * 8];
#pragma unroll
    for (int ni = 0; ni < 4; ni++)
      bf[ni] = *(const bf16x8*)&Bs[(wn * 64 + ni * 16 + (lane & 15)) * 32 + (lane >> 4) * 8];
#pragma unroll
    for (int mi = 0; mi < 4; mi++)
#pragma unroll
      for (int ni = 0; ni < 4; ni++)
        acc[mi][ni] = __builtin_amdgcn_mfma_f32_16x16x32_bf16(af[mi], bf[ni], acc[mi][ni], 0, 0, 0);
  }

  const int quad4 = (lane >> 4) << 2;
  const int c15_ = lane & 15;
#pragma unroll
  for (int mi = 0; mi < 4; mi++) {
    const int m = bm * 128 + wm * 64 + mi * 16 + quad4;   // s base (rows m..m+3)
#pragma unroll
    for (int ni = 0; ni < 4; ni++) {
      const int c = bn * 128 + wn * 64 + ni * 16 + c15_;
      const float bo = ob[c];
      const size_t idx = ((size_t)b * 512 + c) * 1024 + m;
      const float4 xv = *(const float4*)(x + idx);
      float4 ov;
      ov.x = acc[mi][ni][0] + bo + xv.x;
      ov.y = acc[mi][ni][1] + bo + xv.y;
      ov.z = acc[mi][ni][2] + bo + xv.z;
      ov.w = acc[mi][ni][3] + bo + xv.w;
      *(float4*)(out + idx) = ov;
    }
  }
}

extern "C" void kernel_launch(void* const* d_in, const int* in_sizes, int n_in,
                              void* d_out, int out_size, void* d_ws, size_t ws_size,
                              hipStream_t stream) {
  const float* x      = (const float*)d_in[0];
  const float* gn_w   = (const float*)d_in[1];
  const float* gn_b   = (const float*)d_in[2];
  const float* proj_w = (const float*)d_in[3];
  const float* proj_b = (const float*)d_in[4];
  const float* out_w  = (const float*)d_in[5];
  const float* out_b  = (const float*)d_in[6];
  float* out = (float*)d_out;

  char* p = (char*)d_ws;
  u16* h    = (u16*)p; p += (size_t)16 * 1024 * 512 * 2;   // h_img [64mt][16kt][8192]
  u16* q    = (u16*)p; p += (size_t)16 * 8 * 1024 * 64 * 2;
  u16* k    = (u16*)p; p += (size_t)16 * 8 * 1024 * 64 * 2;
  u16* v    = (u16*)p; p += (size_t)16 * 8 * 1024 * 64 * 2;   // [B,H,D,S]
  u16* attn = (u16*)p; p += (size_t)16 * 1024 * 512 * 2;
  u16* wq   = (u16*)p; p += (size_t)1536 * 512 * 2;           // w_img [16nt][16kt][3072]
  u16* wo   = (u16*)p; p += (size_t)512 * 512 * 2;

  gncvt_kernel<<<1536, 256, 0, stream>>>(x, gn_w, gn_b, h, proj_w, out_w, wq, wo);
  qkv_gemm<<<dim3(64, 16), 512, 0, stream>>>(h, wq, proj_b, q, k, v);
  attn_kernel<<<dim3(128, 4), 512, 0, stream>>>(q, k, v, attn);
  out_gemm<<<dim3(8, 4, 16), 256, 0, stream>>>(attn, wo, out_b, x, out);
}

// Round 8
// 193.349 us; speedup vs baseline: 1.0944x; 1.0265x over previous
//
#include <hip/hip_runtime.h>
#include <stdint.h>

typedef unsigned short u16;
typedef __attribute__((ext_vector_type(8))) short bf16x8;
typedef __attribute__((ext_vector_type(4))) short bf16x4;
typedef __attribute__((ext_vector_type(4))) float f32x4;
typedef __attribute__((ext_vector_type(4))) unsigned short u16x4;

// async global->LDS, 16B per lane, dest = wave-uniform base + lane*16
#define GLD16(gp, lp) __builtin_amdgcn_global_load_lds( \
    (__attribute__((address_space(1))) void*)(void*)(gp), \
    (__attribute__((address_space(3))) void*)(void*)(lp), 16, 0, 0)

__device__ __forceinline__ u16 f2b(float f) {  // fp32 -> bf16 bits, RNE
  union { float f; unsigned u; } v; v.f = f;
  unsigned r = v.u + 0x7FFFu + ((v.u >> 16) & 1u);
  return (u16)(r >> 16);
}

__device__ __forceinline__ float fexp2(float x) {
#if __has_builtin(__builtin_amdgcn_exp2f)
  return __builtin_amdgcn_exp2f(x);
#else
  return exp2f(x);
#endif
}

// ============================ LDS-image layouts ============================
// h_img[mt 0..63][kt 0..15][256r x 4chunks]: panel = 8192 u16 (16 KB).
//   slot(r, c8, j) = r*32 + ((c8 ^ ((r>>1)&3))*8) + j    (c8 = 8-ch chunk)
// w_img[nt 0..15][kt 0..15][96r x 4chunks]: panel = 3072 u16 (6 KB), same
//   per-row swizzle. Staging a panel = flat GLD16 copy (1 KB/wave-instr).
// ===========================================================================

// ---------------- fused: GroupNorm (blocks 0..511) + weight cvt (512..1535)
__global__ __launch_bounds__(256) void gncvt_kernel(const float* __restrict__ x,
                                                    const float* __restrict__ gw,
                                                    const float* __restrict__ gb,
                                                    u16* __restrict__ h,
                                                    const float* __restrict__ wq_f,
                                                    const float* __restrict__ wo_f,
                                                    u16* __restrict__ wq,
                                                    u16* __restrict__ wo) {
  if (blockIdx.x >= 512) {
    int i = (blockIdx.x - 512) * 256 + threadIdx.x;   // 0 .. 262143
    if (i < 196608) {
      // proj_w -> w_img: row n = i>>7, channels c0 = (i&127)*4
      const float4 f = ((const float4*)wq_f)[i];
      const int n = i >> 7, c0 = (i & 127) * 4;
      const int nt = n / 96, r = n - nt * 96;
      const int kt = c0 >> 5, c8 = (c0 >> 3) & 3, wi = c0 & 7;
      const int sel = (r >> 1) & 3;
      u16x4 rr; rr[0] = f2b(f.x); rr[1] = f2b(f.y); rr[2] = f2b(f.z); rr[3] = f2b(f.w);
      *(u16x4*)(wq + (size_t)(nt * 16 + kt) * 3072 + r * 32 + ((c8 ^ sel) * 8) + wi) = rr;
    } else {
      int j = i - 196608;
      const float4 f = ((const float4*)wo_f)[j];
      u16x4 rr; rr[0] = f2b(f.x); rr[1] = f2b(f.y); rr[2] = f2b(f.z); rr[3] = f2b(f.w);
      *(u16x4*)(wo + (size_t)j * 4) = rr;
    }
    return;
  }
  const int b = blockIdx.x >> 5, g = blockIdx.x & 31;
  const float* xg = x + ((size_t)(b * 512 + g * 16)) * 1024;
  const int tid = threadIdx.x;
  float4 vals[16];                 // vals[j] = channel j, pixels 4t..4t+3
  float s = 0.f, ss = 0.f;
#pragma unroll
  for (int j = 0; j < 16; j++) {
    const float4 v = ((const float4*)xg)[j * 256 + tid];
    vals[j] = v;
    s  += (v.x + v.y) + (v.z + v.w);
    ss += (v.x * v.x + v.y * v.y) + (v.z * v.z + v.w * v.w);
  }
#pragma unroll
  for (int off = 32; off; off >>= 1) { s += __shfl_down(s, off); ss += __shfl_down(ss, off); }
  __shared__ float red[8];
  const int wid = tid >> 6, lane = tid & 63;
  if (lane == 0) { red[wid] = s; red[4 + wid] = ss; }
  __syncthreads();
  if (tid == 0) {
    float S = red[0] + red[1] + red[2] + red[3];
    float SS = red[4] + red[5] + red[6] + red[7];
    float mean = S * (1.f / 16384.f);
    float var = SS * (1.f / 16384.f) - mean * mean;
    red[0] = mean; red[1] = rsqrtf(var + 1e-5f);
  }
  __syncthreads();
  const float mean = red[0], rs = red[1];
  float sc[16], bi[16];
#pragma unroll
  for (int c = 0; c < 16; c++) { sc[c] = gw[g * 16 + c] * rs; bi[c] = gb[g * 16 + c]; }
  // write into h_img: this block owns chunks {2(g&1), 2(g&1)+1} of kt = g>>1
  const int mt = b * 4 + (tid >> 6);
  const int kt = g >> 1, c8a = (g & 1) * 2;
  u16* base = h + (size_t)(mt * 16 + kt) * 8192;
#pragma unroll
  for (int e = 0; e < 4; e++) {
    const int r = (tid & 63) * 4 + e;
    const int sel = (r >> 1) & 3;
    u16 row[16];
#pragma unroll
    for (int j = 0; j < 16; j++) {
      const float v = (e == 0) ? vals[j].x : (e == 1) ? vals[j].y : (e == 2) ? vals[j].z : vals[j].w;
      row[j] = f2b((v - mean) * sc[j] + bi[j]);
    }
    *(bf16x8*)(base + r * 32 + ((c8a ^ sel) * 8)) = *(bf16x8*)&row[0];
    *(bf16x8*)(base + r * 32 + (((c8a + 1) ^ sel) * 8)) = *(bf16x8*)&row[8];
  }
}

// ---------------- QKV GEMM v6: r5 core + SWAPPED orientation D[ch][s] -----
__global__ __launch_bounds__(512, 4) void qkv_gemm(const u16* __restrict__ h,
                                                   const u16* __restrict__ w,
                                                   const float* __restrict__ bias,
                                                   u16* __restrict__ q,
                                                   u16* __restrict__ k,
                                                   u16* __restrict__ v) {
  __shared__ u16 Hs[2][8192];   // 2 x 16 KB  (h panels: 256 s-rows x 32 ch)
  __shared__ u16 Ws[2][3072];   // 2 x 6 KB   (w panels: 96 ch-rows x 32 ch)
  const int bm = blockIdx.x;    // 0..63  (256 s)
  const int bn = blockIdx.y;    // 0..15  (96 channels)
  const int tid = threadIdx.x, lane = tid & 63, wid = tid >> 6;
  const int wm = wid >> 1, wn = wid & 1;     // wm: 4 s-col waves, wn: 2 ch-row waves
  const int c15 = lane & 15, quad = lane >> 4;
  const int kc = ((quad ^ ((c15 >> 1) & 3)) * 8);   // phys chunk offset (u16)

  const u16* pA = h + (size_t)bm * 16 * 8192 + (size_t)tid * 8;   // + kt*8192
  const u16* pB = w + (size_t)bn * 16 * 3072 + (size_t)tid * 8;   // + kt*3072
  const bool doB = (tid < 384);

  const f32x4 fz = {0.f, 0.f, 0.f, 0.f};
  f32x4 acc[3][4];              // [ch-tile ci][s-tile si]
#pragma unroll
  for (int i = 0; i < 3; i++)
#pragma unroll
    for (int j = 0; j < 4; j++) acc[i][j] = fz;

  // prologue: stage kt=0 into buf 0
  GLD16(pA, &Hs[0][tid * 8]);
  GLD16(pA + 4096, &Hs[0][4096 + tid * 8]);
  if (doB) GLD16(pB, &Ws[0][tid * 8]);
  asm volatile("s_waitcnt vmcnt(0)" ::: "memory");
  __builtin_amdgcn_s_barrier();
  __builtin_amdgcn_sched_barrier(0);

  for (int kt = 0; kt < 16; ++kt) {
    const int cb = kt & 1, db = cb ^ 1;
    if (kt < 15) {   // issue next panel first; ages across this tile's MFMAs
      const u16* nA = pA + (size_t)(kt + 1) * 8192;
      GLD16(nA, &Hs[db][tid * 8]);
      GLD16(nA + 4096, &Hs[db][4096 + tid * 8]);
      if (doB) GLD16(pB + (size_t)(kt + 1) * 3072, &Ws[db][tid * 8]);
      __builtin_amdgcn_sched_barrier(0);
    }
    bf16x8 af[3], bf[4];
#pragma unroll
    for (int ci = 0; ci < 3; ci++)
      af[ci] = *(const bf16x8*)&Ws[cb][(wn * 48 + ci * 16 + c15) * 32 + kc];
#pragma unroll
    for (int si = 0; si < 4; si++)
      bf[si] = *(const bf16x8*)&Hs[cb][(wm * 64 + si * 16 + c15) * 32 + kc];
    __builtin_amdgcn_s_setprio(1);
#pragma unroll
    for (int ci = 0; ci < 3; ci++)
#pragma unroll
      for (int si = 0; si < 4; si++)
        acc[ci][si] = __builtin_amdgcn_mfma_f32_16x16x32_bf16(af[ci], bf[si], acc[ci][si], 0, 0, 0);
    __builtin_amdgcn_s_setprio(0);
    asm volatile("s_waitcnt vmcnt(0)" ::: "memory");   // aged ~full tile
    __builtin_amdgcn_s_barrier();
    __builtin_amdgcn_sched_barrier(0);
  }

  const float qscale = 0.51006972f;            // 2^-1.5 * log2(e)
  const float kscale = 0.35355339059327373f;   // 2^-1.5
  const int b = bm >> 2;
#pragma unroll
  for (int ci = 0; ci < 3; ci++) {
    const int n0 = bn * 96 + wn * 48 + ci * 16 + quad * 4;   // rows n0..n0+3
    const int head = n0 / 192;
    const int rr = n0 - head * 192;
    const int d0 = rr & 63;
    const float4 bi4 = *(const float4*)&bias[n0];
    const float bb[4] = {bi4.x, bi4.y, bi4.z, bi4.w};
#pragma unroll
    for (int si = 0; si < 4; si++) {
      const int sp = (bm & 3) * 256 + wm * 64 + si * 16 + c15;
      if (rr < 128) {
        u16* dst = ((rr < 64) ? q : k) + ((size_t)(b * 8 + head) * 1024 + sp) * 64 + d0;
        const float sc = (rr < 64) ? qscale : kscale;
        u16x4 pk;
#pragma unroll
        for (int r = 0; r < 4; r++) pk[r] = f2b((acc[ci][si][r] + bb[r]) * sc);
        *(u16x4*)dst = pk;
      } else {
#pragma unroll
        for (int r = 0; r < 4; r++)
          v[((size_t)(b * 8 + head) * 64 + d0 + r) * 1024 + sp] = f2b(acc[ci][si][r] + bb[r]);
      }
    }
  }
}

// ---------------- flash attention v11: MFMA-seeded softmax + ones-row lsum -
// v10 structure, two VALU cuts (attn was VALU-bound: 33% VALUBusy > 27% Mfma):
// (1) sacc seeded via MFMA C-operand (fmseed const) on the kk=0 pass -> no
//     per-kt 32x v_mov re-init.
// (2) denominator l computed on the MFMA pipe: accl[ni] += ones^T x P^T
//     (A = constant bf16 1.0 fragment) -> removes 32 VALU adds/kt AND the
//     final cross-lane shfl reduction; numerator and denominator now use
//     identical truncated-p values.
__global__ __launch_bounds__(512) void attn_kernel(const u16* __restrict__ q,
                                                   const u16* __restrict__ k,
                                                   const u16* __restrict__ vT,
                                                   u16* __restrict__ o) {
  __shared__ u16 Ks[2][64 * 64];
  __shared__ u16 Vs[2][64 * 64];
  const int bh = blockIdx.x;
  const int qb = blockIdx.y;      // 0..3
  const int tid = threadIdx.x, lane = tid & 63, wid = tid >> 6;   // wid 0..7
  const u16* Q = q + (size_t)bh * 1024 * 64;
  const u16* K = k + (size_t)bh * 1024 * 64;
  const u16* V = vT + (size_t)bh * 64 * 1024;
  const int qrow0 = qb * 256 + wid * 32;
  const int c15 = lane & 15, quad = lane >> 4;
  const int sw = c15 & 7;                  // read-side swizzle component
  const int srow = tid >> 3;               // 0..63
  const int u8g  = tid & 7;                // 8-col group (K) / 8-key group (V)
  const int s7 = srow & 7;
  const int kld = srow * 64 + ((u8g ^ s7) * 8);
  const int ve = 4 * (u8g >> 2) + 2 * (u8g & 1);   // pc0>>1
  const int vc = ((u8g >> 1) & 1) * 4;             // (pc0&1)*4
  const int vld0 = srow * 64 + ((ve ^ s7) * 8) + vc;
  const int vld1 = srow * 64 + (((ve + 1) ^ s7) * 8) + vc;

  bf16x8 qf[2][2];
#pragma unroll
  for (int kk = 0; kk < 2; kk++)
#pragma unroll
    for (int ni = 0; ni < 2; ni++)
      qf[kk][ni] = *(const bf16x8*)(Q + (size_t)(qrow0 + ni * 16 + c15) * 64 + kk * 32 + quad * 8);

  const f32x4 fz = {0.f, 0.f, 0.f, 0.f};
  const float Mshift = 14.4269504089f;     // 10 * log2(e)
  const f32x4 fmseed = {-Mshift, -Mshift, -Mshift, -Mshift};
  bf16x8 vone;
#pragma unroll
  for (int i = 0; i < 8; i++) vone[i] = (short)0x3F80;   // bf16 1.0
  f32x4 oaccT[4][2];               // O^T[d-tile nd][qrow-tile ni]
#pragma unroll
  for (int i = 0; i < 4; i++)
#pragma unroll
    for (int j = 0; j < 2; j++) oaccT[i][j] = fz;
  f32x4 accl[2] = {fz, fz};        // denominator via ones-MFMA

  bf16x8 kr, vr;
  kr = *(const bf16x8*)(K + (size_t)srow * 64 + u8g * 8);
  vr = *(const bf16x8*)(V + (size_t)srow * 1024 + u8g * 8);
  {
    u16* Kd = Ks[0]; u16* Vd = Vs[0];
    *(bf16x8*)&Kd[kld] = kr;
    union { bf16x4 h[2]; bf16x8 v; } a; a.v = vr;
    *(bf16x4*)&Vd[vld0] = a.h[0];
    *(bf16x4*)&Vd[vld1] = a.h[1];
  }
  kr = *(const bf16x8*)(K + (size_t)(64 + srow) * 64 + u8g * 8);
  vr = *(const bf16x8*)(V + (size_t)srow * 1024 + 64 + u8g * 8);

  for (int kt = 0; kt < 16; ++kt) {
    __syncthreads();   // publish buf[kt&1]; retire readers of buf[(kt&1)^1]
    const int cur = kt & 1, alt = cur ^ 1;
    if (kt < 15) {
      u16* Kd = Ks[alt]; u16* Vd = Vs[alt];
      *(bf16x8*)&Kd[kld] = kr;
      union { bf16x4 h[2]; bf16x8 v; } a; a.v = vr;
      *(bf16x4*)&Vd[vld0] = a.h[0];
      *(bf16x4*)&Vd[vld1] = a.h[1];
      const int pk2 = (kt + 2) & 15;
      kr = *(const bf16x8*)(K + ((size_t)pk2 * 64 + srow) * 64 + u8g * 8);
      vr = *(const bf16x8*)(V + (size_t)srow * 1024 + pk2 * 64 + u8g * 8);
    }
    const u16* Kc = Ks[cur];
    const u16* Vc = Vs[cur];

    // S^T = K Q^T; kk=0 seeds D with fmseed via the C operand (no v_movs)
    f32x4 sacc[4][2];
    {
      bf16x8 af[4];
#pragma unroll
      for (int mi = 0; mi < 4; mi++)
        af[mi] = *(const bf16x8*)&Kc[(mi * 16 + c15) * 64 + (((quad) ^ sw) * 8)];
      __builtin_amdgcn_s_setprio(1);
#pragma unroll
      for (int mi = 0; mi < 4; mi++)
#pragma unroll
        for (int ni = 0; ni < 2; ni++)
          sacc[mi][ni] = __builtin_amdgcn_mfma_f32_16x16x32_bf16(af[mi], qf[0][ni], fmseed, 0, 0, 0);
      __builtin_amdgcn_s_setprio(0);
    }
    {
      bf16x8 af[4];
#pragma unroll
      for (int mi = 0; mi < 4; mi++)
        af[mi] = *(const bf16x8*)&Kc[(mi * 16 + c15) * 64 + (((4 + quad) ^ sw) * 8)];
      __builtin_amdgcn_s_setprio(1);
#pragma unroll
      for (int mi = 0; mi < 4; mi++)
#pragma unroll
        for (int ni = 0; ni < 2; ni++)
          sacc[mi][ni] = __builtin_amdgcn_mfma_f32_16x16x32_bf16(af[mi], qf[1][ni], sacc[mi][ni], 0, 0, 0);
      __builtin_amdgcn_s_setprio(0);
    }

    // P = exp2(s') packed to bf16 pairs IN REGISTERS (truncation)
    unsigned pkd[4][2][2];   // [key-tile mi][ni][dword]
#pragma unroll
    for (int ni = 0; ni < 2; ni++) {
#pragma unroll
      for (int mi = 0; mi < 4; mi++) {
        unsigned pu[4];
#pragma unroll
        for (int r = 0; r < 4; r++) {
          const float p = fexp2(sacc[mi][ni][r]);
          union { float f; unsigned u; } c; c.f = p;
          pu[r] = c.u;
        }
        pkd[mi][ni][0] = __builtin_amdgcn_perm(pu[1], pu[0], 0x07060302u);
        pkd[mi][ni][1] = __builtin_amdgcn_perm(pu[3], pu[2], 0x07060302u);
      }
    }

    // O^T += V^T P^T ; l += ones^T P^T (denominator on the MFMA pipe)
#pragma unroll
    for (int mg = 0; mg < 2; mg++) {
      union { unsigned u[4]; bf16x8 v; } bb[2];
#pragma unroll
      for (int ni = 0; ni < 2; ni++) {
        bb[ni].u[0] = pkd[2 * mg][ni][0];     bb[ni].u[1] = pkd[2 * mg][ni][1];
        bb[ni].u[2] = pkd[2 * mg + 1][ni][0]; bb[ni].u[3] = pkd[2 * mg + 1][ni][1];
      }
      bf16x8 aa[4];
#pragma unroll
      for (int nd = 0; nd < 4; nd++)
        aa[nd] = *(const bf16x8*)&Vc[(nd * 16 + c15) * 64 + (((mg * 4 + quad) ^ sw) * 8)];
      __builtin_amdgcn_s_setprio(1);
#pragma unroll
      for (int nd = 0; nd < 4; nd++)
#pragma unroll
        for (int ni = 0; ni < 2; ni++)
          oaccT[nd][ni] = __builtin_amdgcn_mfma_f32_16x16x32_bf16(aa[nd], bb[ni].v, oaccT[nd][ni], 0, 0, 0);
#pragma unroll
      for (int ni = 0; ni < 2; ni++)
        accl[ni] = __builtin_amdgcn_mfma_f32_16x16x32_bf16(vone, bb[ni].v, accl[ni], 0, 0, 0);
      __builtin_amdgcn_s_setprio(0);
    }
  }

  // denominator already per-qrow in accl (all rows/regs equal) — no shfl
  float iv[2];
#pragma unroll
  for (int ni = 0; ni < 2; ni++) iv[ni] = 1.f / accl[ni][0];
  const int b = bh >> 3, hh = bh & 7;
#pragma unroll
  for (int ni = 0; ni < 2; ni++) {
    const int row = qrow0 + ni * 16 + c15;
#pragma unroll
    for (int nd = 0; nd < 4; nd++) {
      u16x4 pk4;
#pragma unroll
      for (int r = 0; r < 4; r++) pk4[r] = f2b(oaccT[nd][ni][r] * iv[ni]);
      *(u16x4*)(o + ((size_t)b * 1024 + row) * 512 + hh * 64 + nd * 16 + quad * 4) = pk4;
    }
  }
}

// ---------------- out proj, D[s][c] orientation + float4 residual epilogue -
__global__ __launch_bounds__(256) void out_gemm(const u16* __restrict__ attn,
                                                const u16* __restrict__ wo,
                                                const float* __restrict__ ob,
                                                const float* __restrict__ x,
                                                float* __restrict__ out) {
  __shared__ u16 As[128 * 32];
  __shared__ u16 Bs[128 * 32];
  const int b = blockIdx.z;
  const int bm = blockIdx.x;      // s-tile 0..7
  const int bn = blockIdx.y;      // c-tile 0..3
  const int tid = threadIdx.x, lane = tid & 63, wid = tid >> 6;
  const int wm = wid & 1, wn = wid >> 1;
  const u16* gA = attn + ((size_t)b * 1024 + bm * 128) * 512;
  const u16* gB = wo + (size_t)bn * 128 * 512;

  const f32x4 fz = {0.f, 0.f, 0.f, 0.f};
  f32x4 acc[4][4];
#pragma unroll
  for (int i = 0; i < 4; i++)
#pragma unroll
    for (int j = 0; j < 4; j++) acc[i][j] = fz;

  const int r0 = lane >> 2;
  const int ch8 = (lane & 3) * 8;

  for (int kt = 0; kt < 16; ++kt) {
    __syncthreads();
#pragma unroll
    for (int j = 0; j < 2; ++j) {
      const int idx = wid * 2 + j;
      const int row = idx * 16 + r0;
      GLD16(gA + (size_t)row * 512 + kt * 32 + ch8, &As[idx * 512 + lane * 8]);
      GLD16(gB + (size_t)row * 512 + kt * 32 + ch8, &Bs[idx * 512 + lane * 8]);
    }
    __syncthreads();
    bf16x8 af[4], bf[4];
#pragma unroll
    for (int mi = 0; mi < 4; mi++)
      af[mi] = *(const bf16x8*)&As[(wm * 64 + mi * 16 + (lane & 15)) * 32 + (lane >> 4) * 8];
#pragma unroll
    for (int ni = 0; ni < 4; ni++)
      bf[ni] = *(const bf16x8*)&Bs[(wn * 64 + ni * 16 + (lane & 15)) * 32 + (lane >> 4) * 8];
#pragma unroll
    for (int mi = 0; mi < 4; mi++)
#pragma unroll
      for (int ni = 0; ni < 4; ni++)
        acc[mi][ni] = __builtin_amdgcn_mfma_f32_16x16x32_bf16(af[mi], bf[ni], acc[mi][ni], 0, 0, 0);
  }

  const int quad4 = (lane >> 4) << 2;
  const int c15_ = lane & 15;
#pragma unroll
  for (int mi = 0; mi < 4; mi++) {
    const int m = bm * 128 + wm * 64 + mi * 16 + quad4;   // s base (rows m..m+3)
#pragma unroll
    for (int ni = 0; ni < 4; ni++) {
      const int c = bn * 128 + wn * 64 + ni * 16 + c15_;
      const float bo = ob[c];
      const size_t idx = ((size_t)b * 512 + c) * 1024 + m;
      const float4 xv = *(const float4*)(x + idx);
      float4 ov;
      ov.x = acc[mi][ni][0] + bo + xv.x;
      ov.y = acc[mi][ni][1] + bo + xv.y;
      ov.z = acc[mi][ni][2] + bo + xv.z;
      ov.w = acc[mi][ni][3] + bo + xv.w;
      *(float4*)(out + idx) = ov;
    }
  }
}

extern "C" void kernel_launch(void* const* d_in, const int* in_sizes, int n_in,
                              void* d_out, int out_size, void* d_ws, size_t ws_size,
                              hipStream_t stream) {
  const float* x      = (const float*)d_in[0];
  const float* gn_w   = (const float*)d_in[1];
  const float* gn_b   = (const float*)d_in[2];
  const float* proj_w = (const float*)d_in[3];
  const float* proj_b = (const float*)d_in[4];
  const float* out_w  = (const float*)d_in[5];
  const float* out_b  = (const float*)d_in[6];
  float* out = (float*)d_out;

  char* p = (char*)d_ws;
  u16* h    = (u16*)p; p += (size_t)16 * 1024 * 512 * 2;   // h_img [64mt][16kt][8192]
  u16* q    = (u16*)p; p += (size_t)16 * 8 * 1024 * 64 * 2;
  u16* k    = (u16*)p; p += (size_t)16 * 8 * 1024 * 64 * 2;
  u16* v    = (u16*)p; p += (size_t)16 * 8 * 1024 * 64 * 2;   // [B,H,D,S]
  u16* attn = (u16*)p; p += (size_t)16 * 1024 * 512 * 2;
  u16* wq   = (u16*)p; p += (size_t)1536 * 512 * 2;           // w_img [16nt][16kt][3072]
  u16* wo   = (u16*)p; p += (size_t)512 * 512 * 2;

  gncvt_kernel<<<1536, 256, 0, stream>>>(x, gn_w, gn_b, h, proj_w, out_w, wq, wo);
  qkv_gemm<<<dim3(64, 16), 512, 0, stream>>>(h, wq, proj_b, q, k, v);
  attn_kernel<<<dim3(128, 4), 512, 0, stream>>>(q, k, v, attn);
  out_gemm<<<dim3(8, 4, 16), 256, 0, stream>>>(attn, wo, out_b, x, out);
}

// Round 9
// 191.370 us; speedup vs baseline: 1.1057x; 1.0103x over previous
//
#include <hip/hip_runtime.h>
#include <stdint.h>

typedef unsigned short u16;
typedef __attribute__((ext_vector_type(8))) short bf16x8;
typedef __attribute__((ext_vector_type(4))) short bf16x4;
typedef __attribute__((ext_vector_type(4))) float f32x4;
typedef __attribute__((ext_vector_type(4))) unsigned short u16x4;

// async global->LDS, 16B per lane, dest = wave-uniform base + lane*16
#define GLD16(gp, lp) __builtin_amdgcn_global_load_lds( \
    (__attribute__((address_space(1))) void*)(void*)(gp), \
    (__attribute__((address_space(3))) void*)(void*)(lp), 16, 0, 0)

__device__ __forceinline__ u16 f2b(float f) {  // fp32 -> bf16 bits, RNE
  union { float f; unsigned u; } v; v.f = f;
  unsigned r = v.u + 0x7FFFu + ((v.u >> 16) & 1u);
  return (u16)(r >> 16);
}

__device__ __forceinline__ float fexp2(float x) {
#if __has_builtin(__builtin_amdgcn_exp2f)
  return __builtin_amdgcn_exp2f(x);
#else
  return exp2f(x);
#endif
}

// ============================ LDS-image layouts ============================
// h_img[mt 0..63][kt 0..15][256r x 4chunks]: panel = 8192 u16 (16 KB).
//   slot(r, c8, j) = r*32 + ((c8 ^ ((r>>1)&3))*8) + j    (c8 = 8-ch chunk)
// w_img[nt 0..15][kt 0..15][96r x 4chunks]: panel = 3072 u16 (6 KB), same
//   per-row swizzle. Staging a panel = flat GLD16 copy (1 KB/wave-instr).
// ===========================================================================

// ---------------- fused: GroupNorm (blocks 0..511) + weight cvt (512..1535)
__global__ __launch_bounds__(256) void gncvt_kernel(const float* __restrict__ x,
                                                    const float* __restrict__ gw,
                                                    const float* __restrict__ gb,
                                                    u16* __restrict__ h,
                                                    const float* __restrict__ wq_f,
                                                    const float* __restrict__ wo_f,
                                                    u16* __restrict__ wq,
                                                    u16* __restrict__ wo) {
  if (blockIdx.x >= 512) {
    int i = (blockIdx.x - 512) * 256 + threadIdx.x;   // 0 .. 262143
    if (i < 196608) {
      // proj_w -> w_img: row n = i>>7, channels c0 = (i&127)*4
      const float4 f = ((const float4*)wq_f)[i];
      const int n = i >> 7, c0 = (i & 127) * 4;
      const int nt = n / 96, r = n - nt * 96;
      const int kt = c0 >> 5, c8 = (c0 >> 3) & 3, wi = c0 & 7;
      const int sel = (r >> 1) & 3;
      u16x4 rr; rr[0] = f2b(f.x); rr[1] = f2b(f.y); rr[2] = f2b(f.z); rr[3] = f2b(f.w);
      *(u16x4*)(wq + (size_t)(nt * 16 + kt) * 3072 + r * 32 + ((c8 ^ sel) * 8) + wi) = rr;
    } else {
      int j = i - 196608;
      const float4 f = ((const float4*)wo_f)[j];
      u16x4 rr; rr[0] = f2b(f.x); rr[1] = f2b(f.y); rr[2] = f2b(f.z); rr[3] = f2b(f.w);
      *(u16x4*)(wo + (size_t)j * 4) = rr;
    }
    return;
  }
  const int b = blockIdx.x >> 5, g = blockIdx.x & 31;
  const float* xg = x + ((size_t)(b * 512 + g * 16)) * 1024;
  const int tid = threadIdx.x;
  float4 vals[16];                 // vals[j] = channel j, pixels 4t..4t+3
  float s = 0.f, ss = 0.f;
#pragma unroll
  for (int j = 0; j < 16; j++) {
    const float4 v = ((const float4*)xg)[j * 256 + tid];
    vals[j] = v;
    s  += (v.x + v.y) + (v.z + v.w);
    ss += (v.x * v.x + v.y * v.y) + (v.z * v.z + v.w * v.w);
  }
#pragma unroll
  for (int off = 32; off; off >>= 1) { s += __shfl_down(s, off); ss += __shfl_down(ss, off); }
  __shared__ float red[8];
  const int wid = tid >> 6, lane = tid & 63;
  if (lane == 0) { red[wid] = s; red[4 + wid] = ss; }
  __syncthreads();
  if (tid == 0) {
    float S = red[0] + red[1] + red[2] + red[3];
    float SS = red[4] + red[5] + red[6] + red[7];
    float mean = S * (1.f / 16384.f);
    float var = SS * (1.f / 16384.f) - mean * mean;
    red[0] = mean; red[1] = rsqrtf(var + 1e-5f);
  }
  __syncthreads();
  const float mean = red[0], rs = red[1];
  float sc[16], bi[16];
#pragma unroll
  for (int c = 0; c < 16; c++) { sc[c] = gw[g * 16 + c] * rs; bi[c] = gb[g * 16 + c]; }
  // write into h_img: this block owns chunks {2(g&1), 2(g&1)+1} of kt = g>>1
  const int mt = b * 4 + (tid >> 6);
  const int kt = g >> 1, c8a = (g & 1) * 2;
  u16* base = h + (size_t)(mt * 16 + kt) * 8192;
#pragma unroll
  for (int e = 0; e < 4; e++) {
    const int r = (tid & 63) * 4 + e;
    const int sel = (r >> 1) & 3;
    u16 row[16];
#pragma unroll
    for (int j = 0; j < 16; j++) {
      const float v = (e == 0) ? vals[j].x : (e == 1) ? vals[j].y : (e == 2) ? vals[j].z : vals[j].w;
      row[j] = f2b((v - mean) * sc[j] + bi[j]);
    }
    *(bf16x8*)(base + r * 32 + ((c8a ^ sel) * 8)) = *(bf16x8*)&row[0];
    *(bf16x8*)(base + r * 32 + (((c8a + 1) ^ sel) * 8)) = *(bf16x8*)&row[8];
  }
}

// ---------------- QKV GEMM v7: r8 core + 2-deep pipeline (counted vmcnt) --
// SINGLE change vs r8: triple-buffered LDS (66 KB, still 2 blocks/CU) with
// loads issued TWO K-tiles ahead and per-wave counted vmcnt (T4). Loads now
// age ~2 full tiles (>1500 cyc) before the wait -> the ~750-cyc/kt latency
// stall (the invariant across all six prior 48-56us versions) vanishes.
// Fully-unrolled K-loop so buffer indices and wait immediates are
// compile-time. Lw = 3 loads/tile for waves 0-5 (A+A+B), 2 for waves 6-7.
__global__ __launch_bounds__(512, 4) void qkv_gemm(const u16* __restrict__ h,
                                                   const u16* __restrict__ w,
                                                   const float* __restrict__ bias,
                                                   u16* __restrict__ q,
                                                   u16* __restrict__ k,
                                                   u16* __restrict__ v) {
  __shared__ u16 Hs[3][8192];   // 3 x 16 KB
  __shared__ u16 Ws[3][3072];   // 3 x 6 KB
  const int bm = blockIdx.x;    // 0..63  (256 s)
  const int bn = blockIdx.y;    // 0..15  (96 channels)
  const int tid = threadIdx.x, lane = tid & 63, wid = tid >> 6;
  const int wm = wid >> 1, wn = wid & 1;     // wm: 4 s-col waves, wn: 2 ch-row waves
  const int c15 = lane & 15, quad = lane >> 4;
  const int kc = ((quad ^ ((c15 >> 1) & 3)) * 8);   // phys chunk offset (u16)

  const u16* pA = h + (size_t)bm * 16 * 8192 + (size_t)tid * 8;   // + kt*8192
  const u16* pB = w + (size_t)bn * 16 * 3072 + (size_t)tid * 8;   // + kt*3072
  const bool doB = (tid < 384);

  const f32x4 fz = {0.f, 0.f, 0.f, 0.f};
  f32x4 acc[3][4];              // [ch-tile ci][s-tile si]
#pragma unroll
  for (int i = 0; i < 3; i++)
#pragma unroll
    for (int j = 0; j < 4; j++) acc[i][j] = fz;

#define STAGE(T, B) { const u16* a_ = pA + (size_t)(T) * 8192; \
    GLD16(a_, &Hs[B][tid * 8]); \
    GLD16(a_ + 4096, &Hs[B][4096 + tid * 8]); \
    if (doB) GLD16(pB + (size_t)(T) * 3072, &Ws[B][tid * 8]); }

  // prologue: tiles 0,1 in flight
  STAGE(0, 0)
  STAGE(1, 1)

#pragma unroll
  for (int kt = 0; kt < 16; ++kt) {
    const int cb = kt % 3;
    __builtin_amdgcn_s_barrier();      // readers of buf (kt+2)%3 (tile kt-1) done
    if (kt < 14) STAGE(kt + 2, (kt + 2) % 3)
    // counted wait: tile kt's loads are the oldest; leave tiles kt+1,kt+2 in flight
    if (kt < 14) {
      if (doB) asm volatile("s_waitcnt vmcnt(6)" ::: "memory");
      else     asm volatile("s_waitcnt vmcnt(4)" ::: "memory");
    } else if (kt == 14) {
      if (doB) asm volatile("s_waitcnt vmcnt(3)" ::: "memory");
      else     asm volatile("s_waitcnt vmcnt(2)" ::: "memory");
    } else {
      asm volatile("s_waitcnt vmcnt(0)" ::: "memory");
    }
    __builtin_amdgcn_s_barrier();      // publish tile kt (all waves' loads done)
    __builtin_amdgcn_sched_barrier(0);
    bf16x8 af[3], bf[4];
#pragma unroll
    for (int ci = 0; ci < 3; ci++)
      af[ci] = *(const bf16x8*)&Ws[cb][(wn * 48 + ci * 16 + c15) * 32 + kc];
#pragma unroll
    for (int si = 0; si < 4; si++)
      bf[si] = *(const bf16x8*)&Hs[cb][(wm * 64 + si * 16 + c15) * 32 + kc];
    __builtin_amdgcn_s_setprio(1);
#pragma unroll
    for (int ci = 0; ci < 3; ci++)
#pragma unroll
      for (int si = 0; si < 4; si++)
        acc[ci][si] = __builtin_amdgcn_mfma_f32_16x16x32_bf16(af[ci], bf[si], acc[ci][si], 0, 0, 0);
    __builtin_amdgcn_s_setprio(0);
  }
#undef STAGE

  const float qscale = 0.51006972f;            // 2^-1.5 * log2(e)
  const float kscale = 0.35355339059327373f;   // 2^-1.5
  const int b = bm >> 2;
#pragma unroll
  for (int ci = 0; ci < 3; ci++) {
    const int n0 = bn * 96 + wn * 48 + ci * 16 + quad * 4;   // rows n0..n0+3
    const int head = n0 / 192;
    const int rr = n0 - head * 192;
    const int d0 = rr & 63;
    const float4 bi4 = *(const float4*)&bias[n0];
    const float bb[4] = {bi4.x, bi4.y, bi4.z, bi4.w};
#pragma unroll
    for (int si = 0; si < 4; si++) {
      const int sp = (bm & 3) * 256 + wm * 64 + si * 16 + c15;
      if (rr < 128) {
        u16* dst = ((rr < 64) ? q : k) + ((size_t)(b * 8 + head) * 1024 + sp) * 64 + d0;
        const float sc = (rr < 64) ? qscale : kscale;
        u16x4 pk;
#pragma unroll
        for (int r = 0; r < 4; r++) pk[r] = f2b((acc[ci][si][r] + bb[r]) * sc);
        *(u16x4*)dst = pk;
      } else {
#pragma unroll
        for (int r = 0; r < 4; r++)
          v[((size_t)(b * 8 + head) * 64 + d0 + r) * 1024 + sp] = f2b(acc[ci][si][r] + bb[r]);
      }
    }
  }
}

// ---------------- flash attention v11: MFMA-seeded softmax + ones-row lsum -
__global__ __launch_bounds__(512) void attn_kernel(const u16* __restrict__ q,
                                                   const u16* __restrict__ k,
                                                   const u16* __restrict__ vT,
                                                   u16* __restrict__ o) {
  __shared__ u16 Ks[2][64 * 64];
  __shared__ u16 Vs[2][64 * 64];
  const int bh = blockIdx.x;
  const int qb = blockIdx.y;      // 0..3
  const int tid = threadIdx.x, lane = tid & 63, wid = tid >> 6;   // wid 0..7
  const u16* Q = q + (size_t)bh * 1024 * 64;
  const u16* K = k + (size_t)bh * 1024 * 64;
  const u16* V = vT + (size_t)bh * 64 * 1024;
  const int qrow0 = qb * 256 + wid * 32;
  const int c15 = lane & 15, quad = lane >> 4;
  const int sw = c15 & 7;                  // read-side swizzle component
  const int srow = tid >> 3;               // 0..63
  const int u8g  = tid & 7;                // 8-col group (K) / 8-key group (V)
  const int s7 = srow & 7;
  const int kld = srow * 64 + ((u8g ^ s7) * 8);
  const int ve = 4 * (u8g >> 2) + 2 * (u8g & 1);   // pc0>>1
  const int vc = ((u8g >> 1) & 1) * 4;             // (pc0&1)*4
  const int vld0 = srow * 64 + ((ve ^ s7) * 8) + vc;
  const int vld1 = srow * 64 + (((ve + 1) ^ s7) * 8) + vc;

  bf16x8 qf[2][2];
#pragma unroll
  for (int kk = 0; kk < 2; kk++)
#pragma unroll
    for (int ni = 0; ni < 2; ni++)
      qf[kk][ni] = *(const bf16x8*)(Q + (size_t)(qrow0 + ni * 16 + c15) * 64 + kk * 32 + quad * 8);

  const f32x4 fz = {0.f, 0.f, 0.f, 0.f};
  const float Mshift = 14.4269504089f;     // 10 * log2(e)
  const f32x4 fmseed = {-Mshift, -Mshift, -Mshift, -Mshift};
  bf16x8 vone;
#pragma unroll
  for (int i = 0; i < 8; i++) vone[i] = (short)0x3F80;   // bf16 1.0
  f32x4 oaccT[4][2];               // O^T[d-tile nd][qrow-tile ni]
#pragma unroll
  for (int i = 0; i < 4; i++)
#pragma unroll
    for (int j = 0; j < 2; j++) oaccT[i][j] = fz;
  f32x4 accl[2] = {fz, fz};        // denominator via ones-MFMA

  bf16x8 kr, vr;
  kr = *(const bf16x8*)(K + (size_t)srow * 64 + u8g * 8);
  vr = *(const bf16x8*)(V + (size_t)srow * 1024 + u8g * 8);
  {
    u16* Kd = Ks[0]; u16* Vd = Vs[0];
    *(bf16x8*)&Kd[kld] = kr;
    union { bf16x4 h[2]; bf16x8 v; } a; a.v = vr;
    *(bf16x4*)&Vd[vld0] = a.h[0];
    *(bf16x4*)&Vd[vld1] = a.h[1];
  }
  kr = *(const bf16x8*)(K + (size_t)(64 + srow) * 64 + u8g * 8);
  vr = *(const bf16x8*)(V + (size_t)srow * 1024 + 64 + u8g * 8);

  for (int kt = 0; kt < 16; ++kt) {
    __syncthreads();   // publish buf[kt&1]; retire readers of buf[(kt&1)^1]
    const int cur = kt & 1, alt = cur ^ 1;
    if (kt < 15) {
      u16* Kd = Ks[alt]; u16* Vd = Vs[alt];
      *(bf16x8*)&Kd[kld] = kr;
      union { bf16x4 h[2]; bf16x8 v; } a; a.v = vr;
      *(bf16x4*)&Vd[vld0] = a.h[0];
      *(bf16x4*)&Vd[vld1] = a.h[1];
      const int pk2 = (kt + 2) & 15;
      kr = *(const bf16x8*)(K + ((size_t)pk2 * 64 + srow) * 64 + u8g * 8);
      vr = *(const bf16x8*)(V + (size_t)srow * 1024 + pk2 * 64 + u8g * 8);
    }
    const u16* Kc = Ks[cur];
    const u16* Vc = Vs[cur];

    // S^T = K Q^T; kk=0 seeds D with fmseed via the C operand (no v_movs)
    f32x4 sacc[4][2];
    {
      bf16x8 af[4];
#pragma unroll
      for (int mi = 0; mi < 4; mi++)
        af[mi] = *(const bf16x8*)&Kc[(mi * 16 + c15) * 64 + (((quad) ^ sw) * 8)];
      __builtin_amdgcn_s_setprio(1);
#pragma unroll
      for (int mi = 0; mi < 4; mi++)
#pragma unroll
        for (int ni = 0; ni < 2; ni++)
          sacc[mi][ni] = __builtin_amdgcn_mfma_f32_16x16x32_bf16(af[mi], qf[0][ni], fmseed, 0, 0, 0);
      __builtin_amdgcn_s_setprio(0);
    }
    {
      bf16x8 af[4];
#pragma unroll
      for (int mi = 0; mi < 4; mi++)
        af[mi] = *(const bf16x8*)&Kc[(mi * 16 + c15) * 64 + (((4 + quad) ^ sw) * 8)];
      __builtin_amdgcn_s_setprio(1);
#pragma unroll
      for (int mi = 0; mi < 4; mi++)
#pragma unroll
        for (int ni = 0; ni < 2; ni++)
          sacc[mi][ni] = __builtin_amdgcn_mfma_f32_16x16x32_bf16(af[mi], qf[1][ni], sacc[mi][ni], 0, 0, 0);
      __builtin_amdgcn_s_setprio(0);
    }

    // P = exp2(s') packed to bf16 pairs IN REGISTERS (truncation)
    unsigned pkd[4][2][2];   // [key-tile mi][ni][dword]
#pragma unroll
    for (int ni = 0; ni < 2; ni++) {
#pragma unroll
      for (int mi = 0; mi < 4; mi++) {
        unsigned pu[4];
#pragma unroll
        for (int r = 0; r < 4; r++) {
          const float p = fexp2(sacc[mi][ni][r]);
          union { float f; unsigned u; } c; c.f = p;
          pu[r] = c.u;
        }
        pkd[mi][ni][0] = __builtin_amdgcn_perm(pu[1], pu[0], 0x07060302u);
        pkd[mi][ni][1] = __builtin_amdgcn_perm(pu[3], pu[2], 0x07060302u);
      }
    }

    // O^T += V^T P^T ; l += ones^T P^T (denominator on the MFMA pipe)
#pragma unroll
    for (int mg = 0; mg < 2; mg++) {
      union { unsigned u[4]; bf16x8 v; } bb[2];
#pragma unroll
      for (int ni = 0; ni < 2; ni++) {
        bb[ni].u[0] = pkd[2 * mg][ni][0];     bb[ni].u[1] = pkd[2 * mg][ni][1];
        bb[ni].u[2] = pkd[2 * mg + 1][ni][0]; bb[ni].u[3] = pkd[2 * mg + 1][ni][1];
      }
      bf16x8 aa[4];
#pragma unroll
      for (int nd = 0; nd < 4; nd++)
        aa[nd] = *(const bf16x8*)&Vc[(nd * 16 + c15) * 64 + (((mg * 4 + quad) ^ sw) * 8)];
      __builtin_amdgcn_s_setprio(1);
#pragma unroll
      for (int nd = 0; nd < 4; nd++)
#pragma unroll
        for (int ni = 0; ni < 2; ni++)
          oaccT[nd][ni] = __builtin_amdgcn_mfma_f32_16x16x32_bf16(aa[nd], bb[ni].v, oaccT[nd][ni], 0, 0, 0);
#pragma unroll
      for (int ni = 0; ni < 2; ni++)
        accl[ni] = __builtin_amdgcn_mfma_f32_16x16x32_bf16(vone, bb[ni].v, accl[ni], 0, 0, 0);
      __builtin_amdgcn_s_setprio(0);
    }
  }

  // denominator already per-qrow in accl (all rows/regs equal) — no shfl
  float iv[2];
#pragma unroll
  for (int ni = 0; ni < 2; ni++) iv[ni] = 1.f / accl[ni][0];
  const int b = bh >> 3, hh = bh & 7;
#pragma unroll
  for (int ni = 0; ni < 2; ni++) {
    const int row = qrow0 + ni * 16 + c15;
#pragma unroll
    for (int nd = 0; nd < 4; nd++) {
      u16x4 pk4;
#pragma unroll
      for (int r = 0; r < 4; r++) pk4[r] = f2b(oaccT[nd][ni][r] * iv[ni]);
      *(u16x4*)(o + ((size_t)b * 1024 + row) * 512 + hh * 64 + nd * 16 + quad * 4) = pk4;
    }
  }
}

// ---------------- out proj, D[s][c] orientation + float4 residual epilogue -
__global__ __launch_bounds__(256) void out_gemm(const u16* __restrict__ attn,
                                                const u16* __restrict__ wo,
                                                const float* __restrict__ ob,
                                                const float* __restrict__ x,
                                                float* __restrict__ out) {
  __shared__ u16 As[128 * 32];
  __shared__ u16 Bs[128 * 32];
  const int b = blockIdx.z;
  const int bm = blockIdx.x;      // s-tile 0..7
  const int bn = blockIdx.y;      // c-tile 0..3
  const int tid = threadIdx.x, lane = tid & 63, wid = tid >> 6;
  const int wm = wid & 1, wn = wid >> 1;
  const u16* gA = attn + ((size_t)b * 1024 + bm * 128) * 512;
  const u16* gB = wo + (size_t)bn * 128 * 512;

  const f32x4 fz = {0.f, 0.f, 0.f, 0.f};
  f32x4 acc[4][4];
#pragma unroll
  for (int i = 0; i < 4; i++)
#pragma unroll
    for (int j = 0; j < 4; j++) acc[i][j] = fz;

  const int r0 = lane >> 2;
  const int ch8 = (lane & 3) * 8;

  for (int kt = 0; kt < 16; ++kt) {
    __syncthreads();
#pragma unroll
    for (int j = 0; j < 2; ++j) {
      const int idx = wid * 2 + j;
      const int row = idx * 16 + r0;
      GLD16(gA + (size_t)row * 512 + kt * 32 + ch8, &As[idx * 512 + lane * 8]);
      GLD16(gB + (size_t)row * 512 + kt * 32 + ch8, &Bs[idx * 512 + lane * 8]);
    }
    __syncthreads();
    bf16x8 af[4], bf[4];
#pragma unroll
    for (int mi = 0; mi < 4; mi++)
      af[mi] = *(const bf16x8*)&As[(wm * 64 + mi * 16 + (lane & 15)) * 32 + (lane >> 4) * 8];
#pragma unroll
    for (int ni = 0; ni < 4; ni++)
      bf[ni] = *(const bf16x8*)&Bs[(wn * 64 + ni * 16 + (lane & 15)) * 32 + (lane >> 4) * 8];
#pragma unroll
    for (int mi = 0; mi < 4; mi++)
#pragma unroll
      for (int ni = 0; ni < 4; ni++)
        acc[mi][ni] = __builtin_amdgcn_mfma_f32_16x16x32_bf16(af[mi], bf[ni], acc[mi][ni], 0, 0, 0);
  }

  const int quad4 = (lane >> 4) << 2;
  const int c15_ = lane & 15;
#pragma unroll
  for (int mi = 0; mi < 4; mi++) {
    const int m = bm * 128 + wm * 64 + mi * 16 + quad4;   // s base (rows m..m+3)
#pragma unroll
    for (int ni = 0; ni < 4; ni++) {
      const int c = bn * 128 + wn * 64 + ni * 16 + c15_;
      const float bo = ob[c];
      const size_t idx = ((size_t)b * 512 + c) * 1024 + m;
      const float4 xv = *(const float4*)(x + idx);
      float4 ov;
      ov.x = acc[mi][ni][0] + bo + xv.x;
      ov.y = acc[mi][ni][1] + bo + xv.y;
      ov.z = acc[mi][ni][2] + bo + xv.z;
      ov.w = acc[mi][ni][3] + bo + xv.w;
      *(float4*)(out + idx) = ov;
    }
  }
}

extern "C" void kernel_launch(void* const* d_in, const int* in_sizes, int n_in,
                              void* d_out, int out_size, void* d_ws, size_t ws_size,
                              hipStream_t stream) {
  const float* x      = (const float*)d_in[0];
  const float* gn_w   = (const float*)d_in[1];
  const float* gn_b   = (const float*)d_in[2];
  const float* proj_w = (const float*)d_in[3];
  const float* proj_b = (const float*)d_in[4];
  const float* out_w  = (const float*)d_in[5];
  const float* out_b  = (const float*)d_in[6];
  float* out = (float*)d_out;

  char* p = (char*)d_ws;
  u16* h    = (u16*)p; p += (size_t)16 * 1024 * 512 * 2;   // h_img [64mt][16kt][8192]
  u16* q    = (u16*)p; p += (size_t)16 * 8 * 1024 * 64 * 2;
  u16* k    = (u16*)p; p += (size_t)16 * 8 * 1024 * 64 * 2;
  u16* v    = (u16*)p; p += (size_t)16 * 8 * 1024 * 64 * 2;   // [B,H,D,S]
  u16* attn = (u16*)p; p += (size_t)16 * 1024 * 512 * 2;
  u16* wq   = (u16*)p; p += (size_t)1536 * 512 * 2;           // w_img [16nt][16kt][3072]
  u16* wo   = (u16*)p; p += (size_t)512 * 512 * 2;

  gncvt_kernel<<<1536, 256, 0, stream>>>(x, gn_w, gn_b, h, proj_w, out_w, wq, wo);
  qkv_gemm<<<dim3(64, 16), 512, 0, stream>>>(h, wq, proj_b, q, k, v);
  attn_kernel<<<dim3(128, 4), 512, 0, stream>>>(q, k, v, attn);
  out_gemm<<<dim3(8, 4, 16), 256, 0, stream>>>(attn, wo, out_b, x, out);
}

// Round 10
// 189.769 us; speedup vs baseline: 1.1150x; 1.0084x over previous
//
#include <hip/hip_runtime.h>
#include <stdint.h>

typedef unsigned short u16;
typedef __attribute__((ext_vector_type(8))) short bf16x8;
typedef __attribute__((ext_vector_type(4))) short bf16x4;
typedef __attribute__((ext_vector_type(4))) float f32x4;
typedef __attribute__((ext_vector_type(4))) unsigned short u16x4;

// async global->LDS, 16B per lane, dest = wave-uniform base + lane*16
#define GLD16(gp, lp) __builtin_amdgcn_global_load_lds( \
    (__attribute__((address_space(1))) void*)(void*)(gp), \
    (__attribute__((address_space(3))) void*)(void*)(lp), 16, 0, 0)

__device__ __forceinline__ u16 f2b(float f) {  // fp32 -> bf16 bits, RNE
  union { float f; unsigned u; } v; v.f = f;
  unsigned r = v.u + 0x7FFFu + ((v.u >> 16) & 1u);
  return (u16)(r >> 16);
}

__device__ __forceinline__ float fexp2(float x) {
#if __has_builtin(__builtin_amdgcn_exp2f)
  return __builtin_amdgcn_exp2f(x);
#else
  return exp2f(x);
#endif
}

// ============================ LDS-image layouts ============================
// h_img[mt 0..63][kt 0..15][256r x 4chunks]: panel = 8192 u16 (16 KB).
//   slot(r, c8, j) = r*32 + ((c8 ^ ((r>>1)&3))*8) + j    (c8 = 8-ch chunk)
// w_img[nt 0..15][kt 0..15][96r x 4chunks]: panel = 3072 u16 (6 KB), same
//   per-row swizzle. Staging a panel = flat GLD16 copy (1 KB/wave-instr).
// ===========================================================================

// ---------------- fused: GroupNorm (blocks 0..511) + weight cvt (512..1535)
__global__ __launch_bounds__(256) void gncvt_kernel(const float* __restrict__ x,
                                                    const float* __restrict__ gw,
                                                    const float* __restrict__ gb,
                                                    u16* __restrict__ h,
                                                    const float* __restrict__ wq_f,
                                                    const float* __restrict__ wo_f,
                                                    u16* __restrict__ wq,
                                                    u16* __restrict__ wo) {
  if (blockIdx.x >= 512) {
    int i = (blockIdx.x - 512) * 256 + threadIdx.x;   // 0 .. 262143
    if (i < 196608) {
      // proj_w -> w_img: row n = i>>7, channels c0 = (i&127)*4
      const float4 f = ((const float4*)wq_f)[i];
      const int n = i >> 7, c0 = (i & 127) * 4;
      const int nt = n / 96, r = n - nt * 96;
      const int kt = c0 >> 5, c8 = (c0 >> 3) & 3, wi = c0 & 7;
      const int sel = (r >> 1) & 3;
      u16x4 rr; rr[0] = f2b(f.x); rr[1] = f2b(f.y); rr[2] = f2b(f.z); rr[3] = f2b(f.w);
      *(u16x4*)(wq + (size_t)(nt * 16 + kt) * 3072 + r * 32 + ((c8 ^ sel) * 8) + wi) = rr;
    } else {
      int j = i - 196608;
      const float4 f = ((const float4*)wo_f)[j];
      u16x4 rr; rr[0] = f2b(f.x); rr[1] = f2b(f.y); rr[2] = f2b(f.z); rr[3] = f2b(f.w);
      *(u16x4*)(wo + (size_t)j * 4) = rr;
    }
    return;
  }
  const int b = blockIdx.x >> 5, g = blockIdx.x & 31;
  const float* xg = x + ((size_t)(b * 512 + g * 16)) * 1024;
  const int tid = threadIdx.x;
  float4 vals[16];                 // vals[j] = channel j, pixels 4t..4t+3
  float s = 0.f, ss = 0.f;
#pragma unroll
  for (int j = 0; j < 16; j++) {
    const float4 v = ((const float4*)xg)[j * 256 + tid];
    vals[j] = v;
    s  += (v.x + v.y) + (v.z + v.w);
    ss += (v.x * v.x + v.y * v.y) + (v.z * v.z + v.w * v.w);
  }
#pragma unroll
  for (int off = 32; off; off >>= 1) { s += __shfl_down(s, off); ss += __shfl_down(ss, off); }
  __shared__ float red[8];
  const int wid = tid >> 6, lane = tid & 63;
  if (lane == 0) { red[wid] = s; red[4 + wid] = ss; }
  __syncthreads();
  if (tid == 0) {
    float S = red[0] + red[1] + red[2] + red[3];
    float SS = red[4] + red[5] + red[6] + red[7];
    float mean = S * (1.f / 16384.f);
    float var = SS * (1.f / 16384.f) - mean * mean;
    red[0] = mean; red[1] = rsqrtf(var + 1e-5f);
  }
  __syncthreads();
  const float mean = red[0], rs = red[1];
  float sc[16], bi[16];
#pragma unroll
  for (int c = 0; c < 16; c++) { sc[c] = gw[g * 16 + c] * rs; bi[c] = gb[g * 16 + c]; }
  // write into h_img: this block owns chunks {2(g&1), 2(g&1)+1} of kt = g>>1
  const int mt = b * 4 + (tid >> 6);
  const int kt = g >> 1, c8a = (g & 1) * 2;
  u16* base = h + (size_t)(mt * 16 + kt) * 8192;
#pragma unroll
  for (int e = 0; e < 4; e++) {
    const int r = (tid & 63) * 4 + e;
    const int sel = (r >> 1) & 3;
    u16 row[16];
#pragma unroll
    for (int j = 0; j < 16; j++) {
      const float v = (e == 0) ? vals[j].x : (e == 1) ? vals[j].y : (e == 2) ? vals[j].z : vals[j].w;
      row[j] = f2b((v - mean) * sc[j] + bi[j]);
    }
    *(bf16x8*)(base + r * 32 + ((c8a ^ sel) * 8)) = *(bf16x8*)&row[0];
    *(bf16x8*)(base + r * 32 + (((c8a + 1) ^ sel) * 8)) = *(bf16x8*)&row[8];
  }
}

// ---------------- QKV GEMM v7: 2-deep pipeline (counted vmcnt) ------------
__global__ __launch_bounds__(512, 4) void qkv_gemm(const u16* __restrict__ h,
                                                   const u16* __restrict__ w,
                                                   const float* __restrict__ bias,
                                                   u16* __restrict__ q,
                                                   u16* __restrict__ k,
                                                   u16* __restrict__ v) {
  __shared__ u16 Hs[3][8192];   // 3 x 16 KB
  __shared__ u16 Ws[3][3072];   // 3 x 6 KB
  const int bm = blockIdx.x;    // 0..63  (256 s)
  const int bn = blockIdx.y;    // 0..15  (96 channels)
  const int tid = threadIdx.x, lane = tid & 63, wid = tid >> 6;
  const int wm = wid >> 1, wn = wid & 1;     // wm: 4 s-col waves, wn: 2 ch-row waves
  const int c15 = lane & 15, quad = lane >> 4;
  const int kc = ((quad ^ ((c15 >> 1) & 3)) * 8);   // phys chunk offset (u16)

  const u16* pA = h + (size_t)bm * 16 * 8192 + (size_t)tid * 8;   // + kt*8192
  const u16* pB = w + (size_t)bn * 16 * 3072 + (size_t)tid * 8;   // + kt*3072
  const bool doB = (tid < 384);

  const f32x4 fz = {0.f, 0.f, 0.f, 0.f};
  f32x4 acc[3][4];              // [ch-tile ci][s-tile si]
#pragma unroll
  for (int i = 0; i < 3; i++)
#pragma unroll
    for (int j = 0; j < 4; j++) acc[i][j] = fz;

#define STAGE(T, B) { const u16* a_ = pA + (size_t)(T) * 8192; \
    GLD16(a_, &Hs[B][tid * 8]); \
    GLD16(a_ + 4096, &Hs[B][4096 + tid * 8]); \
    if (doB) GLD16(pB + (size_t)(T) * 3072, &Ws[B][tid * 8]); }

  // prologue: tiles 0,1 in flight
  STAGE(0, 0)
  STAGE(1, 1)

#pragma unroll
  for (int kt = 0; kt < 16; ++kt) {
    const int cb = kt % 3;
    __builtin_amdgcn_s_barrier();      // readers of buf (kt+2)%3 (tile kt-1) done
    if (kt < 14) STAGE(kt + 2, (kt + 2) % 3)
    // counted wait: tile kt's loads are the oldest; leave tiles kt+1,kt+2 in flight
    if (kt < 14) {
      if (doB) asm volatile("s_waitcnt vmcnt(6)" ::: "memory");
      else     asm volatile("s_waitcnt vmcnt(4)" ::: "memory");
    } else if (kt == 14) {
      if (doB) asm volatile("s_waitcnt vmcnt(3)" ::: "memory");
      else     asm volatile("s_waitcnt vmcnt(2)" ::: "memory");
    } else {
      asm volatile("s_waitcnt vmcnt(0)" ::: "memory");
    }
    __builtin_amdgcn_s_barrier();      // publish tile kt (all waves' loads done)
    __builtin_amdgcn_sched_barrier(0);
    bf16x8 af[3], bf[4];
#pragma unroll
    for (int ci = 0; ci < 3; ci++)
      af[ci] = *(const bf16x8*)&Ws[cb][(wn * 48 + ci * 16 + c15) * 32 + kc];
#pragma unroll
    for (int si = 0; si < 4; si++)
      bf[si] = *(const bf16x8*)&Hs[cb][(wm * 64 + si * 16 + c15) * 32 + kc];
    __builtin_amdgcn_s_setprio(1);
#pragma unroll
    for (int ci = 0; ci < 3; ci++)
#pragma unroll
      for (int si = 0; si < 4; si++)
        acc[ci][si] = __builtin_amdgcn_mfma_f32_16x16x32_bf16(af[ci], bf[si], acc[ci][si], 0, 0, 0);
    __builtin_amdgcn_s_setprio(0);
  }
#undef STAGE

  const float qscale = 0.51006972f;            // 2^-1.5 * log2(e)
  const float kscale = 0.35355339059327373f;   // 2^-1.5
  const int b = bm >> 2;
#pragma unroll
  for (int ci = 0; ci < 3; ci++) {
    const int n0 = bn * 96 + wn * 48 + ci * 16 + quad * 4;   // rows n0..n0+3
    const int head = n0 / 192;
    const int rr = n0 - head * 192;
    const int d0 = rr & 63;
    const float4 bi4 = *(const float4*)&bias[n0];
    const float bb[4] = {bi4.x, bi4.y, bi4.z, bi4.w};
#pragma unroll
    for (int si = 0; si < 4; si++) {
      const int sp = (bm & 3) * 256 + wm * 64 + si * 16 + c15;
      if (rr < 128) {
        u16* dst = ((rr < 64) ? q : k) + ((size_t)(b * 8 + head) * 1024 + sp) * 64 + d0;
        const float sc = (rr < 64) ? qscale : kscale;
        u16x4 pk;
#pragma unroll
        for (int r = 0; r < 4; r++) pk[r] = f2b((acc[ci][si][r] + bb[r]) * sc);
        *(u16x4*)dst = pk;
      } else {
#pragma unroll
        for (int r = 0; r < 4; r++)
          v[((size_t)(b * 8 + head) * 64 + d0 + r) * 1024 + sp] = f2b(acc[ci][si][r] + bb[r]);
      }
    }
  }
}

// ---------------- flash attention v11: MFMA-seeded softmax + ones-row lsum -
__global__ __launch_bounds__(512) void attn_kernel(const u16* __restrict__ q,
                                                   const u16* __restrict__ k,
                                                   const u16* __restrict__ vT,
                                                   u16* __restrict__ o) {
  __shared__ u16 Ks[2][64 * 64];
  __shared__ u16 Vs[2][64 * 64];
  const int bh = blockIdx.x;
  const int qb = blockIdx.y;      // 0..3
  const int tid = threadIdx.x, lane = tid & 63, wid = tid >> 6;   // wid 0..7
  const u16* Q = q + (size_t)bh * 1024 * 64;
  const u16* K = k + (size_t)bh * 1024 * 64;
  const u16* V = vT + (size_t)bh * 64 * 1024;
  const int qrow0 = qb * 256 + wid * 32;
  const int c15 = lane & 15, quad = lane >> 4;
  const int sw = c15 & 7;                  // read-side swizzle component
  const int srow = tid >> 3;               // 0..63
  const int u8g  = tid & 7;                // 8-col group (K) / 8-key group (V)
  const int s7 = srow & 7;
  const int kld = srow * 64 + ((u8g ^ s7) * 8);
  const int ve = 4 * (u8g >> 2) + 2 * (u8g & 1);   // pc0>>1
  const int vc = ((u8g >> 1) & 1) * 4;             // (pc0&1)*4
  const int vld0 = srow * 64 + ((ve ^ s7) * 8) + vc;
  const int vld1 = srow * 64 + (((ve + 1) ^ s7) * 8) + vc;

  bf16x8 qf[2][2];
#pragma unroll
  for (int kk = 0; kk < 2; kk++)
#pragma unroll
    for (int ni = 0; ni < 2; ni++)
      qf[kk][ni] = *(const bf16x8*)(Q + (size_t)(qrow0 + ni * 16 + c15) * 64 + kk * 32 + quad * 8);

  const f32x4 fz = {0.f, 0.f, 0.f, 0.f};
  const float Mshift = 14.4269504089f;     // 10 * log2(e)
  const f32x4 fmseed = {-Mshift, -Mshift, -Mshift, -Mshift};
  bf16x8 vone;
#pragma unroll
  for (int i = 0; i < 8; i++) vone[i] = (short)0x3F80;   // bf16 1.0
  f32x4 oaccT[4][2];               // O^T[d-tile nd][qrow-tile ni]
#pragma unroll
  for (int i = 0; i < 4; i++)
#pragma unroll
    for (int j = 0; j < 2; j++) oaccT[i][j] = fz;
  f32x4 accl[2] = {fz, fz};        // denominator via ones-MFMA

  bf16x8 kr, vr;
  kr = *(const bf16x8*)(K + (size_t)srow * 64 + u8g * 8);
  vr = *(const bf16x8*)(V + (size_t)srow * 1024 + u8g * 8);
  {
    u16* Kd = Ks[0]; u16* Vd = Vs[0];
    *(bf16x8*)&Kd[kld] = kr;
    union { bf16x4 h[2]; bf16x8 v; } a; a.v = vr;
    *(bf16x4*)&Vd[vld0] = a.h[0];
    *(bf16x4*)&Vd[vld1] = a.h[1];
  }
  kr = *(const bf16x8*)(K + (size_t)(64 + srow) * 64 + u8g * 8);
  vr = *(const bf16x8*)(V + (size_t)srow * 1024 + 64 + u8g * 8);

  for (int kt = 0; kt < 16; ++kt) {
    __syncthreads();   // publish buf[kt&1]; retire readers of buf[(kt&1)^1]
    const int cur = kt & 1, alt = cur ^ 1;
    if (kt < 15) {
      u16* Kd = Ks[alt]; u16* Vd = Vs[alt];
      *(bf16x8*)&Kd[kld] = kr;
      union { bf16x4 h[2]; bf16x8 v; } a; a.v = vr;
      *(bf16x4*)&Vd[vld0] = a.h[0];
      *(bf16x4*)&Vd[vld1] = a.h[1];
      const int pk2 = (kt + 2) & 15;
      kr = *(const bf16x8*)(K + ((size_t)pk2 * 64 + srow) * 64 + u8g * 8);
      vr = *(const bf16x8*)(V + (size_t)srow * 1024 + pk2 * 64 + u8g * 8);
    }
    const u16* Kc = Ks[cur];
    const u16* Vc = Vs[cur];

    // S^T = K Q^T; kk=0 seeds D with fmseed via the C operand (no v_movs)
    f32x4 sacc[4][2];
    {
      bf16x8 af[4];
#pragma unroll
      for (int mi = 0; mi < 4; mi++)
        af[mi] = *(const bf16x8*)&Kc[(mi * 16 + c15) * 64 + (((quad) ^ sw) * 8)];
      __builtin_amdgcn_s_setprio(1);
#pragma unroll
      for (int mi = 0; mi < 4; mi++)
#pragma unroll
        for (int ni = 0; ni < 2; ni++)
          sacc[mi][ni] = __builtin_amdgcn_mfma_f32_16x16x32_bf16(af[mi], qf[0][ni], fmseed, 0, 0, 0);
      __builtin_amdgcn_s_setprio(0);
    }
    {
      bf16x8 af[4];
#pragma unroll
      for (int mi = 0; mi < 4; mi++)
        af[mi] = *(const bf16x8*)&Kc[(mi * 16 + c15) * 64 + (((4 + quad) ^ sw) * 8)];
      __builtin_amdgcn_s_setprio(1);
#pragma unroll
      for (int mi = 0; mi < 4; mi++)
#pragma unroll
        for (int ni = 0; ni < 2; ni++)
          sacc[mi][ni] = __builtin_amdgcn_mfma_f32_16x16x32_bf16(af[mi], qf[1][ni], sacc[mi][ni], 0, 0, 0);
      __builtin_amdgcn_s_setprio(0);
    }

    // P = exp2(s') packed to bf16 pairs IN REGISTERS (truncation)
    unsigned pkd[4][2][2];   // [key-tile mi][ni][dword]
#pragma unroll
    for (int ni = 0; ni < 2; ni++) {
#pragma unroll
      for (int mi = 0; mi < 4; mi++) {
        unsigned pu[4];
#pragma unroll
        for (int r = 0; r < 4; r++) {
          const float p = fexp2(sacc[mi][ni][r]);
          union { float f; unsigned u; } c; c.f = p;
          pu[r] = c.u;
        }
        pkd[mi][ni][0] = __builtin_amdgcn_perm(pu[1], pu[0], 0x07060302u);
        pkd[mi][ni][1] = __builtin_amdgcn_perm(pu[3], pu[2], 0x07060302u);
      }
    }

    // O^T += V^T P^T ; l += ones^T P^T (denominator on the MFMA pipe)
#pragma unroll
    for (int mg = 0; mg < 2; mg++) {
      union { unsigned u[4]; bf16x8 v; } bb[2];
#pragma unroll
      for (int ni = 0; ni < 2; ni++) {
        bb[ni].u[0] = pkd[2 * mg][ni][0];     bb[ni].u[1] = pkd[2 * mg][ni][1];
        bb[ni].u[2] = pkd[2 * mg + 1][ni][0]; bb[ni].u[3] = pkd[2 * mg + 1][ni][1];
      }
      bf16x8 aa[4];
#pragma unroll
      for (int nd = 0; nd < 4; nd++)
        aa[nd] = *(const bf16x8*)&Vc[(nd * 16 + c15) * 64 + (((mg * 4 + quad) ^ sw) * 8)];
      __builtin_amdgcn_s_setprio(1);
#pragma unroll
      for (int nd = 0; nd < 4; nd++)
#pragma unroll
        for (int ni = 0; ni < 2; ni++)
          oaccT[nd][ni] = __builtin_amdgcn_mfma_f32_16x16x32_bf16(aa[nd], bb[ni].v, oaccT[nd][ni], 0, 0, 0);
#pragma unroll
      for (int ni = 0; ni < 2; ni++)
        accl[ni] = __builtin_amdgcn_mfma_f32_16x16x32_bf16(vone, bb[ni].v, accl[ni], 0, 0, 0);
      __builtin_amdgcn_s_setprio(0);
    }
  }

  // denominator already per-qrow in accl (all rows/regs equal) — no shfl
  float iv[2];
#pragma unroll
  for (int ni = 0; ni < 2; ni++) iv[ni] = 1.f / accl[ni][0];
  const int b = bh >> 3, hh = bh & 7;
#pragma unroll
  for (int ni = 0; ni < 2; ni++) {
    const int row = qrow0 + ni * 16 + c15;
#pragma unroll
    for (int nd = 0; nd < 4; nd++) {
      u16x4 pk4;
#pragma unroll
      for (int r = 0; r < 4; r++) pk4[r] = f2b(oaccT[nd][ni][r] * iv[ni]);
      *(u16x4*)(o + ((size_t)b * 1024 + row) * 512 + hh * 64 + nd * 16 + quad * 4) = pk4;
    }
  }
}

// ---------------- out proj v2: 2-deep counted-vmcnt pipeline --------------
// Port of qkv v7's proven schedule: triple-buffered LDS (48 KB), loads issued
// TWO K-tiles ahead, uniform 4 GLD16/thread/tile -> steady-state vmcnt(8)
// (tiles kt+1,kt+2 in flight), tail 4 -> 0. Staging addresses, tile geometry
// (128^2, 256 thr, acc[4][4]) and the float4 residual epilogue unchanged.
__global__ __launch_bounds__(256) void out_gemm(const u16* __restrict__ attn,
                                                const u16* __restrict__ wo,
                                                const float* __restrict__ ob,
                                                const float* __restrict__ x,
                                                float* __restrict__ out) {
  __shared__ u16 As[3][4096];   // 3 x 8 KB
  __shared__ u16 Bs[3][4096];   // 3 x 8 KB
  const int b = blockIdx.z;
  const int bm = blockIdx.x;      // s-tile 0..7
  const int bn = blockIdx.y;      // c-tile 0..3
  const int tid = threadIdx.x, lane = tid & 63, wid = tid >> 6;
  const int wm = wid & 1, wn = wid >> 1;
  const u16* gA = attn + ((size_t)b * 1024 + bm * 128) * 512;
  const u16* gB = wo + (size_t)bn * 128 * 512;

  const f32x4 fz = {0.f, 0.f, 0.f, 0.f};
  f32x4 acc[4][4];
#pragma unroll
  for (int i = 0; i < 4; i++)
#pragma unroll
    for (int j = 0; j < 4; j++) acc[i][j] = fz;

  const int r0 = lane >> 2;
  const int ch8 = (lane & 3) * 8;

#define OSTAGE(T, B) { \
    _Pragma("unroll") \
    for (int j_ = 0; j_ < 2; ++j_) { \
      const int idx_ = wid * 2 + j_; \
      const int row_ = idx_ * 16 + r0; \
      GLD16(gA + (size_t)row_ * 512 + (T) * 32 + ch8, &As[B][idx_ * 512 + lane * 8]); \
      GLD16(gB + (size_t)row_ * 512 + (T) * 32 + ch8, &Bs[B][idx_ * 512 + lane * 8]); \
    } }

  // prologue: tiles 0,1 in flight (8 loads/thread)
  OSTAGE(0, 0)
  OSTAGE(1, 1)

#pragma unroll
  for (int kt = 0; kt < 16; ++kt) {
    const int cb = kt % 3;
    __builtin_amdgcn_s_barrier();      // readers of buf (kt+2)%3 (tile kt-1) done
    if (kt < 14) OSTAGE(kt + 2, (kt + 2) % 3)
    // counted wait: tile kt's 4 loads are the oldest outstanding
    if (kt < 14)       asm volatile("s_waitcnt vmcnt(8)" ::: "memory");
    else if (kt == 14) asm volatile("s_waitcnt vmcnt(4)" ::: "memory");
    else               asm volatile("s_waitcnt vmcnt(0)" ::: "memory");
    __builtin_amdgcn_s_barrier();      // publish tile kt
    __builtin_amdgcn_sched_barrier(0);
    bf16x8 af[4], bf[4];
#pragma unroll
    for (int mi = 0; mi < 4; mi++)
      af[mi] = *(const bf16x8*)&As[cb][(wm * 64 + mi * 16 + (lane & 15)) * 32 + (lane >> 4) * 8];
#pragma unroll
    for (int ni = 0; ni < 4; ni++)
      bf[ni] = *(const bf16x8*)&Bs[cb][(wn * 64 + ni * 16 + (lane & 15)) * 32 + (lane >> 4) * 8];
    __builtin_amdgcn_s_setprio(1);
#pragma unroll
    for (int mi = 0; mi < 4; mi++)
#pragma unroll
      for (int ni = 0; ni < 4; ni++)
        acc[mi][ni] = __builtin_amdgcn_mfma_f32_16x16x32_bf16(af[mi], bf[ni], acc[mi][ni], 0, 0, 0);
    __builtin_amdgcn_s_setprio(0);
  }
#undef OSTAGE

  const int quad4 = (lane >> 4) << 2;
  const int c15_ = lane & 15;
#pragma unroll
  for (int mi = 0; mi < 4; mi++) {
    const int m = bm * 128 + wm * 64 + mi * 16 + quad4;   // s base (rows m..m+3)
#pragma unroll
    for (int ni = 0; ni < 4; ni++) {
      const int c = bn * 128 + wn * 64 + ni * 16 + c15_;
      const float bo = ob[c];
      const size_t idx = ((size_t)b * 512 + c) * 1024 + m;
      const float4 xv = *(const float4*)(x + idx);
      float4 ov;
      ov.x = acc[mi][ni][0] + bo + xv.x;
      ov.y = acc[mi][ni][1] + bo + xv.y;
      ov.z = acc[mi][ni][2] + bo + xv.z;
      ov.w = acc[mi][ni][3] + bo + xv.w;
      *(float4*)(out + idx) = ov;
    }
  }
}

extern "C" void kernel_launch(void* const* d_in, const int* in_sizes, int n_in,
                              void* d_out, int out_size, void* d_ws, size_t ws_size,
                              hipStream_t stream) {
  const float* x      = (const float*)d_in[0];
  const float* gn_w   = (const float*)d_in[1];
  const float* gn_b   = (const float*)d_in[2];
  const float* proj_w = (const float*)d_in[3];
  const float* proj_b = (const float*)d_in[4];
  const float* out_w  = (const float*)d_in[5];
  const float* out_b  = (const float*)d_in[6];
  float* out = (float*)d_out;

  char* p = (char*)d_ws;
  u16* h    = (u16*)p; p += (size_t)16 * 1024 * 512 * 2;   // h_img [64mt][16kt][8192]
  u16* q    = (u16*)p; p += (size_t)16 * 8 * 1024 * 64 * 2;
  u16* k    = (u16*)p; p += (size_t)16 * 8 * 1024 * 64 * 2;
  u16* v    = (u16*)p; p += (size_t)16 * 8 * 1024 * 64 * 2;   // [B,H,D,S]
  u16* attn = (u16*)p; p += (size_t)16 * 1024 * 512 * 2;
  u16* wq   = (u16*)p; p += (size_t)1536 * 512 * 2;           // w_img [16nt][16kt][3072]
  u16* wo   = (u16*)p; p += (size_t)512 * 512 * 2;

  gncvt_kernel<<<1536, 256, 0, stream>>>(x, gn_w, gn_b, h, proj_w, out_w, wq, wo);
  qkv_gemm<<<dim3(64, 16), 512, 0, stream>>>(h, wq, proj_b, q, k, v);
  attn_kernel<<<dim3(128, 4), 512, 0, stream>>>(q, k, v, attn);
  out_gemm<<<dim3(8, 4, 16), 256, 0, stream>>>(attn, wo, out_b, x, out);
}